// Round 1
// baseline (2133.793 us; speedup 1.0000x reference)
//
#include <hip/hip_runtime.h>

typedef unsigned short u16;

#define DIMM   192
#define DEPTH  12
#define NHEAD  3
#define DHEADD 64
#define MLPD   768
#define NCLS   35
#define NTOK   99
#define TIMG   98
#define FIMG   40
#define NBATCH 512
#define MT     7

// LDS layout (u16 element offsets)
#define XS_S 200
#define QH_S 72
#define VT_S 136
#define P_S  136
#define XS0  0
#define QH0  22400
#define KH0  30464
#define VT0  38528
#define P0   47232
#define RR_BYTE 124928
#define SMEM_BYTES 128512

typedef __attribute__((ext_vector_type(8))) __bf16 bf8;
typedef __attribute__((ext_vector_type(4))) float  f4;

__device__ __forceinline__ float b2f(u16 u){
  union { float f; unsigned u; } v; v.u = ((unsigned)u) << 16; return v.f;
}
__device__ __forceinline__ u16 f2b(float f){
  union { float f; unsigned u; } v; v.f = f;
  unsigned r = v.u + 0x7FFFu + ((v.u >> 16) & 1u);
  return (u16)(r >> 16);
}
__device__ __forceinline__ f4 mm(bf8 a, bf8 b, f4 c){
  return __builtin_amdgcn_mfma_f32_16x16x32_bf16(a, b, c, 0, 0, 0);
}
__device__ __forceinline__ float gelu_f(float x){
  float z = x * 0.7071067811865476f;
  float az = fabsf(z);
  float t = 1.0f / (1.0f + 0.3275911f * az);
  float poly = ((((1.061405429f*t - 1.453152027f)*t + 1.421413741f)*t
                 - 0.284496736f)*t + 0.254829592f)*t;
  float erfv = 1.0f - poly * __expf(-az*az);
  erfv = (z < 0.0f) ? -erfv : erfv;
  return 0.5f * x * (1.0f + erfv);
}

// Pre-permute weights: f32 [layers][K][N] -> bf16 fragment order
// dst[(((layer*NT+nt)*KT+kt)*64 + lane)*8 + j] = W[layer][kt*32+(lane>>4)*8+j][nt*16+(lane&15)]
extern "C" __global__ void permw(const float* __restrict__ src, u16* __restrict__ dst,
                                 int total, int KT, int NT, int realK, int Ndim){
  int i = blockIdx.x * 256 + threadIdx.x;
  if (i >= total) return;
  int j = i & 7, l = (i >> 3) & 63;
  int rest = i >> 9;
  int kt = rest % KT; rest /= KT;
  int nt = rest % NT; int layer = rest / NT;
  int k = kt*32 + (l>>4)*8 + j;
  int n = nt*16 + (l&15);
  float v = (k < realK) ? src[((size_t)layer*realK + k)*Ndim + n] : 0.0f;
  dst[i] = f2b(v);
}

__device__ __forceinline__ void epilogue_ln(
    f4 (&acc)[MT][3], u16* sm, float* rowred,
    const float* gptr, const float* bptr, const float* biasptr,
    int wv, int lg, int lr)
{
  float gg[3], bb[3], ob[3];
#pragma unroll
  for (int nt = 0; nt < 3; ++nt) {
    int c = wv*48 + nt*16 + lr;
    gg[nt] = gptr[c]; bb[nt] = bptr[c]; ob[nt] = biasptr[c];
  }
#pragma unroll
  for (int mt = 0; mt < MT; ++mt) {
#pragma unroll
    for (int r = 0; r < 4; ++r) {
      int row = mt*16 + lg*4 + r;
      float s1 = 0.f, s2 = 0.f;
#pragma unroll
      for (int nt = 0; nt < 3; ++nt) {
        int c = wv*48 + nt*16 + lr;
        float v = acc[mt][nt][r] + ob[nt] + b2f(sm[XS0 + row*XS_S + c]);
        acc[mt][nt][r] = v;
        s1 += v; s2 += v*v;
      }
      s1 += __shfl_xor(s1,1); s2 += __shfl_xor(s2,1);
      s1 += __shfl_xor(s1,2); s2 += __shfl_xor(s2,2);
      s1 += __shfl_xor(s1,4); s2 += __shfl_xor(s2,4);
      s1 += __shfl_xor(s1,8); s2 += __shfl_xor(s2,8);
      if (lr == 0) {
        rowred[(row*4 + wv)*2 + 0] = s1;
        rowred[(row*4 + wv)*2 + 1] = s2;
      }
    }
  }
  __syncthreads();
#pragma unroll
  for (int mt = 0; mt < MT; ++mt) {
#pragma unroll
    for (int r = 0; r < 4; ++r) {
      int row = mt*16 + lg*4 + r;
      float S1 = rowred[row*8+0]+rowred[row*8+2]+rowred[row*8+4]+rowred[row*8+6];
      float S2 = rowred[row*8+1]+rowred[row*8+3]+rowred[row*8+5]+rowred[row*8+7];
      float mean = S1 * (1.0f/DIMM);
      float var  = S2 * (1.0f/DIMM) - mean*mean;
      float rs = rsqrtf(var + 1e-5f);
      if (row < NTOK) {
#pragma unroll
        for (int nt = 0; nt < 3; ++nt) {
          int c = wv*48 + nt*16 + lr;
          float y = (acc[mt][nt][r] - mean)*rs*gg[nt] + bb[nt];
          sm[XS0 + row*XS_S + c] = f2b(y);
        }
      }
    }
  }
  __syncthreads();
}

extern "C" __global__ __launch_bounds__(256, 1) void vit_main(
    const float* __restrict__ img,   const float* __restrict__ g_feat,
    const float* __restrict__ pos_emb,
    const float* __restrict__ ln1_g, const float* __restrict__ ln1_b,
    const float* __restrict__ ln2_g, const float* __restrict__ ln2_b,
    const float* __restrict__ out_b, const float* __restrict__ ff1_b,
    const float* __restrict__ ff2_b,
    const float* __restrict__ hln_g, const float* __restrict__ hln_b,
    const float* __restrict__ head_w, const float* __restrict__ head_b,
    const u16* __restrict__ wlin, const u16* __restrict__ wqkv,
    const u16* __restrict__ wout, const u16* __restrict__ wff1,
    const u16* __restrict__ wff2,
    float* __restrict__ out)
{
  extern __shared__ __align__(16) u16 sm[];
  float* rowred = (float*)((char*)sm + RR_BYTE);
  const int tid  = threadIdx.x;
  const int lane = tid & 63;
  const int wv   = tid >> 6;
  const int lg   = lane >> 4;
  const int lr   = lane & 15;
  const int b    = blockIdx.x;

  // zero all LDS once (pad rows of xs must stay 0 forever)
  for (int i = tid; i < SMEM_BYTES/4; i += 256) ((unsigned*)sm)[i] = 0u;
  __syncthreads();

  // ---- patch embed: stage img (shifted +1 row; row0 = cls slot) into QH region ----
  const float* imgb = img + (size_t)b * (TIMG*FIMG);
  for (int i = tid; i < TIMG*FIMG; i += 256) {
    int r = i / FIMG, c = i - r*FIMG;
    sm[QH0 + (r+1)*QH_S + c] = f2b(imgb[i]);
  }
  __syncthreads();
  {
    bf8 Bf[3][2];
#pragma unroll
    for (int nt = 0; nt < 3; ++nt)
#pragma unroll
      for (int kt = 0; kt < 2; ++kt)
        Bf[nt][kt] = *(const bf8*)&wlin[(((wv*3+nt)*2 + kt)*64 + lane)*8];
    for (int mt = 0; mt < MT; ++mt) {
      bf8 Af[2];
#pragma unroll
      for (int kt = 0; kt < 2; ++kt)
        Af[kt] = *(const bf8*)&sm[QH0 + (mt*16+lr)*QH_S + kt*32 + lg*8];
#pragma unroll
      for (int nt = 0; nt < 3; ++nt) {
        f4 a = {0.f,0.f,0.f,0.f};
#pragma unroll
        for (int kt = 0; kt < 2; ++kt) a = mm(Af[kt], Bf[nt][kt], a);
        int col = (wv*3+nt)*16 + lr;
#pragma unroll
        for (int r = 0; r < 4; ++r) {
          int row = mt*16 + lg*4 + r;
          if (row < NTOK) {
            float v = a[r] + pos_emb[row*DIMM + col] + (row==0 ? g_feat[col] : 0.f);
            sm[XS0 + row*XS_S + col] = f2b(v);
          }
        }
      }
    }
  }
  __syncthreads();

  const f4 zero4 = {0.f,0.f,0.f,0.f};

  for (int L = 0; L < DEPTH; ++L) {
    // ================= attention =================
    f4 oacc[MT][3];
#pragma unroll
    for (int mt = 0; mt < MT; ++mt)
#pragma unroll
      for (int nt = 0; nt < 3; ++nt) oacc[mt][nt] = zero4;

    for (int h = 0; h < NHEAD; ++h) {
      // (A) qkv GEMM: wave wv does q/k/v N-subtile wv of this head
      {
        const u16* wq = wqkv + (size_t)L*36*6*512;
        const int ntq = h*4 + wv, ntk = 12 + h*4 + wv, ntv = 24 + h*4 + wv;
        bf8 Bq[6], Bk[6], Bv[6];
#pragma unroll
        for (int kt = 0; kt < 6; ++kt) {
          Bq[kt] = *(const bf8*)&wq[((ntq*6 + kt)*64 + lane)*8];
          Bk[kt] = *(const bf8*)&wq[((ntk*6 + kt)*64 + lane)*8];
          Bv[kt] = *(const bf8*)&wq[((ntv*6 + kt)*64 + lane)*8];
        }
        for (int mt = 0; mt < MT; ++mt) {
          bf8 Af[6];
#pragma unroll
          for (int kt = 0; kt < 6; ++kt)
            Af[kt] = *(const bf8*)&sm[XS0 + (mt*16+lr)*XS_S + kt*32 + lg*8];
          f4 aq = zero4, ak = zero4, av = zero4;
#pragma unroll
          for (int kt = 0; kt < 6; ++kt) {
            aq = mm(Af[kt], Bq[kt], aq);
            ak = mm(Af[kt], Bk[kt], ak);
            av = mm(Af[kt], Bv[kt], av);
          }
          const int colq = wv*16 + lr;
#pragma unroll
          for (int r = 0; r < 4; ++r) {
            int row = mt*16 + lg*4 + r;
            sm[QH0 + row*QH_S + colq] = f2b(aq[r]*0.125f);   // Q pre-scaled
            sm[KH0 + row*QH_S + colq] = f2b(ak[r]);
            sm[VT0 + colq*VT_S + row] = f2b(av[r]);          // V transposed
          }
        }
        // zero V^T pad key-cols 112..127
        for (int i = tid; i < 64*16; i += 256)
          sm[VT0 + (i>>4)*VT_S + 112 + (i&15)] = 0;
      }
      __syncthreads();

      // (B)+(C): per-wave M-tiles: S = QK^T, softmax, P, O = P V
#pragma unroll
      for (int mi = 0; mi < 2; ++mi) {
        int mt = wv + mi*4;
        if (mt < MT) {
          bf8 Aq[2];
#pragma unroll
          for (int ks = 0; ks < 2; ++ks)
            Aq[ks] = *(const bf8*)&sm[QH0 + (mt*16+lr)*QH_S + ks*32 + lg*8];
          f4 s[7];
#pragma unroll
          for (int kt = 0; kt < 7; ++kt) {
            f4 a = zero4;
#pragma unroll
            for (int ks = 0; ks < 2; ++ks) {
              bf8 Bk2 = *(const bf8*)&sm[KH0 + (kt*16+lr)*QH_S + ks*32 + lg*8];
              a = mm(Aq[ks], Bk2, a);
            }
            s[kt] = a;
          }
#pragma unroll
          for (int r = 0; r < 4; ++r) {
            const int row = mt*16 + lg*4 + r;
            float m = -1e30f;
#pragma unroll
            for (int kt = 0; kt < 7; ++kt) {
              float v = ((kt*16 + lr) < NTOK) ? s[kt][r] : -1e30f;
              m = fmaxf(m, v);
            }
            m = fmaxf(m, __shfl_xor(m, 1));
            m = fmaxf(m, __shfl_xor(m, 2));
            m = fmaxf(m, __shfl_xor(m, 4));
            m = fmaxf(m, __shfl_xor(m, 8));
            float p[7]; float sum = 0.f;
#pragma unroll
            for (int kt = 0; kt < 7; ++kt) {
              p[kt] = ((kt*16 + lr) < NTOK) ? __expf(s[kt][r] - m) : 0.f;
              sum += p[kt];
            }
            sum += __shfl_xor(sum, 1);
            sum += __shfl_xor(sum, 2);
            sum += __shfl_xor(sum, 4);
            sum += __shfl_xor(sum, 8);
            float inv = 1.0f / sum;
#pragma unroll
            for (int kt = 0; kt < 7; ++kt)
              sm[P0 + row*P_S + kt*16 + lr] = f2b(p[kt]*inv);
            sm[P0 + row*P_S + 112 + lr] = 0;
          }
          asm volatile("" ::: "memory");  // keep P writes before A-frag reads
          bf8 Ap[4];
#pragma unroll
          for (int ks = 0; ks < 4; ++ks)
            Ap[ks] = *(const bf8*)&sm[P0 + (mt*16+lr)*P_S + ks*32 + lg*8];
#pragma unroll
          for (int nt = 0; nt < 4; ++nt) {
            f4 a = zero4;
#pragma unroll
            for (int ks = 0; ks < 4; ++ks) {
              bf8 Bv2 = *(const bf8*)&sm[VT0 + (nt*16+lr)*VT_S + ks*32 + lg*8];
              a = mm(Ap[ks], Bv2, a);
            }
            const int col = nt*16 + lr;
#pragma unroll
            for (int r = 0; r < 4; ++r) {
              int row = mt*16 + lg*4 + r;
              sm[QH0 + row*QH_S + col] = f2b(a[r]);  // o_h into QH (own rows)
            }
          }
        }
      }
      __syncthreads();

      // (D) out-proj accumulate: oacc += o_h @ out_w[64h:64h+64, :]
      {
        bf8 Bo[3][2];
#pragma unroll
        for (int nt = 0; nt < 3; ++nt)
#pragma unroll
          for (int ks = 0; ks < 2; ++ks)
            Bo[nt][ks] = *(const bf8*)&wout[(size_t)(((L*12 + wv*3+nt)*6 + (h*2+ks))*64 + lane)*8];
#pragma unroll
        for (int mt = 0; mt < MT; ++mt) {
          bf8 Ao[2];
#pragma unroll
          for (int ks = 0; ks < 2; ++ks)
            Ao[ks] = *(const bf8*)&sm[QH0 + (mt*16+lr)*QH_S + ks*32 + lg*8];
#pragma unroll
          for (int nt = 0; nt < 3; ++nt)
#pragma unroll
            for (int ks = 0; ks < 2; ++ks)
              oacc[mt][nt] = mm(Ao[ks], Bo[nt][ks], oacc[mt][nt]);
        }
      }
      __syncthreads();
    } // heads

    epilogue_ln(oacc, sm, rowred, ln1_g + L*DIMM, ln1_b + L*DIMM, out_b + L*DIMM, wv, lg, lr);

    // ================= MLP =================
    f4 facc[MT][3];
#pragma unroll
    for (int mt = 0; mt < MT; ++mt)
#pragma unroll
      for (int nt = 0; nt < 3; ++nt) facc[mt][nt] = zero4;

    for (int blk = 0; blk < 4; ++blk) {
      { // GEMM1 + gelu -> h_lds (QH region, stride XS_S)
        bf8 B1[3][6];
#pragma unroll
        for (int nt = 0; nt < 3; ++nt)
#pragma unroll
          for (int kt = 0; kt < 6; ++kt)
            B1[nt][kt] = *(const bf8*)&wff1[(size_t)(((L*48 + blk*12 + wv*3+nt)*6 + kt)*64 + lane)*8];
        float fb[3];
#pragma unroll
        for (int nt = 0; nt < 3; ++nt)
          fb[nt] = ff1_b[L*MLPD + blk*192 + (wv*3+nt)*16 + lr];
        for (int mt = 0; mt < MT; ++mt) {
          bf8 Af[6];
#pragma unroll
          for (int kt = 0; kt < 6; ++kt)
            Af[kt] = *(const bf8*)&sm[XS0 + (mt*16+lr)*XS_S + kt*32 + lg*8];
#pragma unroll
          for (int nt = 0; nt < 3; ++nt) {
            f4 a = zero4;
#pragma unroll
            for (int kt = 0; kt < 6; ++kt) a = mm(Af[kt], B1[nt][kt], a);
            int col = (wv*3+nt)*16 + lr;
#pragma unroll
            for (int r = 0; r < 4; ++r) {
              int row = mt*16 + lg*4 + r;
              sm[QH0 + row*XS_S + col] = f2b(gelu_f(a[r] + fb[nt]));
            }
          }
        }
      }
      __syncthreads();
      { // GEMM2 accumulate
        bf8 B2[3][6];
#pragma unroll
        for (int nt = 0; nt < 3; ++nt)
#pragma unroll
          for (int kt = 0; kt < 6; ++kt)
            B2[nt][kt] = *(const bf8*)&wff2[(size_t)(((L*12 + wv*3+nt)*24 + blk*6 + kt)*64 + lane)*8];
#pragma unroll
        for (int mt = 0; mt < MT; ++mt) {
          bf8 Ah[6];
#pragma unroll
          for (int kt = 0; kt < 6; ++kt)
            Ah[kt] = *(const bf8*)&sm[QH0 + (mt*16+lr)*XS_S + kt*32 + lg*8];
#pragma unroll
          for (int nt = 0; nt < 3; ++nt)
#pragma unroll
            for (int kt = 0; kt < 6; ++kt)
              facc[mt][nt] = mm(Ah[kt], B2[nt][kt], facc[mt][nt]);
        }
      }
      __syncthreads();
    }

    epilogue_ln(facc, sm, rowred, ln2_g + L*DIMM, ln2_b + L*DIMM, ff2_b + L*DIMM, wv, lg, lr);
  } // layers

  // ================= head =================
  float* yv = rowred;
  if (wv == 0) {
    float x0 = b2f(sm[XS0 + lane]);
    float x1 = b2f(sm[XS0 + 64 + lane]);
    float x2 = b2f(sm[XS0 + 128 + lane]);
    float s1 = x0+x1+x2;
    float s2 = x0*x0 + x1*x1 + x2*x2;
#pragma unroll
    for (int d = 1; d < 64; d <<= 1) { s1 += __shfl_xor(s1, d); s2 += __shfl_xor(s2, d); }
    float mean = s1*(1.0f/DIMM), var = s2*(1.0f/DIMM) - mean*mean;
    float rs = rsqrtf(var + 1e-5f);
    yv[lane]      = (x0-mean)*rs*hln_g[lane]      + hln_b[lane];
    yv[64+lane]   = (x1-mean)*rs*hln_g[64+lane]   + hln_b[64+lane];
    yv[128+lane]  = (x2-mean)*rs*hln_g[128+lane]  + hln_b[128+lane];
  }
  __syncthreads();
  if (tid < NCLS) {
    float acc = head_b[tid];
    for (int k = 0; k < DIMM; ++k) acc += yv[k] * head_w[k*NCLS + tid];
    out[(size_t)b*NCLS + tid] = acc;
  }
}

extern "C" void kernel_launch(void* const* d_in, const int* in_sizes, int n_in,
                              void* d_out, int out_size, void* d_ws, size_t ws_size,
                              hipStream_t stream) {
  const float* img    = (const float*)d_in[0];
  const float* lin_w  = (const float*)d_in[1];
  const float* g_feat = (const float*)d_in[2];
  const float* pos_emb= (const float*)d_in[3];
  const float* ln1_g  = (const float*)d_in[4];
  const float* ln1_b  = (const float*)d_in[5];
  const float* ln2_g  = (const float*)d_in[6];
  const float* ln2_b  = (const float*)d_in[7];
  const float* qkv_w  = (const float*)d_in[8];
  const float* out_w  = (const float*)d_in[9];
  const float* out_b  = (const float*)d_in[10];
  const float* ff1_w  = (const float*)d_in[11];
  const float* ff1_b  = (const float*)d_in[12];
  const float* ff2_w  = (const float*)d_in[13];
  const float* ff2_b  = (const float*)d_in[14];
  const float* hln_g  = (const float*)d_in[15];
  const float* hln_b  = (const float*)d_in[16];
  const float* head_w = (const float*)d_in[17];
  const float* head_b = (const float*)d_in[18];

  u16* ws   = (u16*)d_ws;
  u16* wlin = ws;                   // 1*12*2*512    = 12288
  u16* wqkv = wlin + 12288;         // 12*36*6*512   = 1327104
  u16* wout = wqkv + 1327104;       // 12*12*6*512   = 442368
  u16* wff1 = wout + 442368;        // 12*48*6*512   = 1769472
  u16* wff2 = wff1 + 1769472;       // 12*12*24*512  = 1769472

  struct PermArgs { const float* src; u16* dst; int layers, Kdim, Ndim, realK; };
  const PermArgs pa[5] = {
    { lin_w, wlin, 1, 64, 192, 40 },
    { qkv_w, wqkv, 12, 192, 576, 192 },
    { out_w, wout, 12, 192, 192, 192 },
    { ff1_w, wff1, 12, 192, 768, 192 },
    { ff2_w, wff2, 12, 768, 192, 768 },
  };
  for (int i = 0; i < 5; ++i) {
    int total = pa[i].layers * (pa[i].Ndim/16) * (pa[i].Kdim/32) * 512;
    hipLaunchKernelGGL(permw, dim3((total + 255)/256), dim3(256), 0, stream,
                       pa[i].src, pa[i].dst, total, pa[i].Kdim/32, pa[i].Ndim/16,
                       pa[i].realK, pa[i].Ndim);
  }

  hipFuncSetAttribute(reinterpret_cast<const void*>(vit_main),
                      hipFuncAttributeMaxDynamicSharedMemorySize, SMEM_BYTES);

  hipLaunchKernelGGL(vit_main, dim3(NBATCH), dim3(256), SMEM_BYTES, stream,
                     img, g_feat, pos_emb, ln1_g, ln1_b, ln2_g, ln2_b,
                     out_b, ff1_b, ff2_b, hln_g, hln_b, head_w, head_b,
                     wlin, wqkv, wout, wff1, wff2, (float*)d_out);
}

// Round 2
// 1834.045 us; speedup vs baseline: 1.1634x; 1.1634x over previous
//
#include <hip/hip_runtime.h>

typedef unsigned short u16;

#define DIMM   192
#define DEPTH  12
#define NHEAD  3
#define DHEADD 64
#define MLPD   768
#define NCLS   35
#define NTOK   99
#define TIMG   98
#define FIMG   40
#define NBATCH 512
#define MT     7

// LDS layout (u16 element offsets)
#define XS_S 200
#define QH_S 72
#define VT_S 136
#define P_S  136
#define XS0  0
#define QH0  22400
#define KH0  30464
#define VT0  38528
#define P0   47232
#define RR_BYTE 124928
#define SMEM_BYTES 128512

typedef __attribute__((ext_vector_type(8))) __bf16 bf8;
typedef __attribute__((ext_vector_type(4))) float  f4;

__device__ __forceinline__ float b2f(u16 u){
  union { float f; unsigned u; } v; v.u = ((unsigned)u) << 16; return v.f;
}
__device__ __forceinline__ u16 f2b(float f){
  union { float f; unsigned u; } v; v.f = f;
  unsigned r = v.u + 0x7FFFu + ((v.u >> 16) & 1u);
  return (u16)(r >> 16);
}
__device__ __forceinline__ f4 mm(bf8 a, bf8 b, f4 c){
  return __builtin_amdgcn_mfma_f32_16x16x32_bf16(a, b, c, 0, 0, 0);
}
__device__ __forceinline__ float gelu_f(float x){
  float z = x * 0.7071067811865476f;
  float az = fabsf(z);
  float t = 1.0f / (1.0f + 0.3275911f * az);
  float poly = ((((1.061405429f*t - 1.453152027f)*t + 1.421413741f)*t
                 - 0.284496736f)*t + 0.254829592f)*t;
  float erfv = 1.0f - poly * __expf(-az*az);
  erfv = (z < 0.0f) ? -erfv : erfv;
  return 0.5f * x * (1.0f + erfv);
}

// Pre-permute weights: f32 [layers][K][N] -> bf16 fragment order
extern "C" __global__ void permw(const float* __restrict__ src, u16* __restrict__ dst,
                                 int total, int KT, int NT, int realK, int Ndim){
  int i = blockIdx.x * 256 + threadIdx.x;
  if (i >= total) return;
  int j = i & 7, l = (i >> 3) & 63;
  int rest = i >> 9;
  int kt = rest % KT; rest /= KT;
  int nt = rest % NT; int layer = rest / NT;
  int k = kt*32 + (l>>4)*8 + j;
  int n = nt*16 + (l&15);
  float v = (k < realK) ? src[((size_t)layer*realK + k)*Ndim + n] : 0.0f;
  dst[i] = f2b(v);
}

// 8-wave epilogue: waves = 2 M-groups (wm) x 4 N-groups (wn)
__device__ __forceinline__ void epilogue_ln(
    f4 (&acc)[4][3], u16* sm, float* rowred,
    const float* gptr, const float* bptr, const float* biasptr,
    int wm, int wn, int lg, int lr)
{
  float gg[3], bb[3], ob[3];
#pragma unroll
  for (int nt = 0; nt < 3; ++nt) {
    int c = wn*48 + nt*16 + lr;
    gg[nt] = gptr[c]; bb[nt] = bptr[c]; ob[nt] = biasptr[c];
  }
#pragma unroll
  for (int mi = 0; mi < 4; ++mi) {
    int mt = wm*4 + mi;
    if (mt < MT) {
#pragma unroll
      for (int r = 0; r < 4; ++r) {
        int row = mt*16 + lg*4 + r;
        float s1 = 0.f, s2 = 0.f;
#pragma unroll
        for (int nt = 0; nt < 3; ++nt) {
          int c = wn*48 + nt*16 + lr;
          float v = acc[mi][nt][r] + ob[nt] + b2f(sm[XS0 + row*XS_S + c]);
          acc[mi][nt][r] = v;
          s1 += v; s2 += v*v;
        }
        s1 += __shfl_xor(s1,1); s2 += __shfl_xor(s2,1);
        s1 += __shfl_xor(s1,2); s2 += __shfl_xor(s2,2);
        s1 += __shfl_xor(s1,4); s2 += __shfl_xor(s2,4);
        s1 += __shfl_xor(s1,8); s2 += __shfl_xor(s2,8);
        if (lr == 0) {
          rowred[(row*4 + wn)*2 + 0] = s1;
          rowred[(row*4 + wn)*2 + 1] = s2;
        }
      }
    }
  }
  __syncthreads();
#pragma unroll
  for (int mi = 0; mi < 4; ++mi) {
    int mt = wm*4 + mi;
    if (mt < MT) {
#pragma unroll
      for (int r = 0; r < 4; ++r) {
        int row = mt*16 + lg*4 + r;
        float S1 = rowred[row*8+0]+rowred[row*8+2]+rowred[row*8+4]+rowred[row*8+6];
        float S2 = rowred[row*8+1]+rowred[row*8+3]+rowred[row*8+5]+rowred[row*8+7];
        float mean = S1 * (1.0f/DIMM);
        float var  = S2 * (1.0f/DIMM) - mean*mean;
        float rs = rsqrtf(var + 1e-5f);
        if (row < NTOK) {
#pragma unroll
          for (int nt = 0; nt < 3; ++nt) {
            int c = wn*48 + nt*16 + lr;
            float y = (acc[mi][nt][r] - mean)*rs*gg[nt] + bb[nt];
            sm[XS0 + row*XS_S + c] = f2b(y);
          }
        }
      }
    }
  }
  __syncthreads();
}

extern "C" __global__ __launch_bounds__(512, 1) void vit_main(
    const float* __restrict__ img,   const float* __restrict__ g_feat,
    const float* __restrict__ pos_emb,
    const float* __restrict__ ln1_g, const float* __restrict__ ln1_b,
    const float* __restrict__ ln2_g, const float* __restrict__ ln2_b,
    const float* __restrict__ out_b, const float* __restrict__ ff1_b,
    const float* __restrict__ ff2_b,
    const float* __restrict__ hln_g, const float* __restrict__ hln_b,
    const float* __restrict__ head_w, const float* __restrict__ head_b,
    const u16* __restrict__ wlin, const u16* __restrict__ wqkv,
    const u16* __restrict__ wout, const u16* __restrict__ wff1,
    const u16* __restrict__ wff2,
    float* __restrict__ out)
{
  extern __shared__ __align__(16) u16 sm[];
  float* rowred = (float*)((char*)sm + RR_BYTE);
  const int tid  = threadIdx.x;
  const int lane = tid & 63;
  const int wv   = tid >> 6;     // 0..7
  const int wm   = wv >> 2;      // M-group: rows wm*64..
  const int wn   = wv & 3;       // N-group: cols wn*48..
  const int lg   = lane >> 4;
  const int lr   = lane & 15;
  const int b    = blockIdx.x;

  // zero all LDS once (pad regions must stay 0 forever)
  for (int i = tid; i < SMEM_BYTES/4; i += 512) ((unsigned*)sm)[i] = 0u;
  __syncthreads();

  // ---- patch embed: stage img (shifted +1 row; row0 = cls slot) into QH region ----
  const float* imgb = img + (size_t)b * (TIMG*FIMG);
  for (int i = tid; i < TIMG*FIMG; i += 512) {
    int r = i / FIMG, c = i - r*FIMG;
    sm[QH0 + (r+1)*QH_S + c] = f2b(imgb[i]);
  }
  __syncthreads();
  {
    bf8 Bf[3][2];
#pragma unroll
    for (int nt = 0; nt < 3; ++nt)
#pragma unroll
      for (int kt = 0; kt < 2; ++kt)
        Bf[nt][kt] = *(const bf8*)&wlin[(((wn*3+nt)*2 + kt)*64 + lane)*8];
#pragma unroll
    for (int mi = 0; mi < 4; ++mi) {
      int mt = wm*4 + mi;
      if (mt < MT) {
        bf8 Af[2];
#pragma unroll
        for (int kt = 0; kt < 2; ++kt)
          Af[kt] = *(const bf8*)&sm[QH0 + (mt*16+lr)*QH_S + kt*32 + lg*8];
#pragma unroll
        for (int nt = 0; nt < 3; ++nt) {
          f4 a = {0.f,0.f,0.f,0.f};
#pragma unroll
          for (int kt = 0; kt < 2; ++kt) a = mm(Af[kt], Bf[nt][kt], a);
          int col = (wn*3+nt)*16 + lr;
#pragma unroll
          for (int r = 0; r < 4; ++r) {
            int row = mt*16 + lg*4 + r;
            if (row < NTOK) {
              float v = a[r] + pos_emb[row*DIMM + col] + (row==0 ? g_feat[col] : 0.f);
              sm[XS0 + row*XS_S + col] = f2b(v);
            }
          }
        }
      }
    }
  }
  __syncthreads();

  const f4 zero4 = {0.f,0.f,0.f,0.f};

  for (int L = 0; L < DEPTH; ++L) {
    // ================= attention =================
    f4 oacc[4][3];
#pragma unroll
    for (int mi = 0; mi < 4; ++mi)
#pragma unroll
      for (int nt = 0; nt < 3; ++nt) oacc[mi][nt] = zero4;

    for (int h = 0; h < NHEAD; ++h) {
      // (A) qkv GEMM: wave (wm,wn) does q/k/v N-subtile wn, M-group wm
      {
        const u16* wq = wqkv + (size_t)L*36*6*512;
        const int ntq = h*4 + wn, ntk = 12 + h*4 + wn, ntv = 24 + h*4 + wn;
        bf8 Bq[6], Bk[6], Bv[6];
#pragma unroll
        for (int kt = 0; kt < 6; ++kt) {
          Bq[kt] = *(const bf8*)&wq[((ntq*6 + kt)*64 + lane)*8];
          Bk[kt] = *(const bf8*)&wq[((ntk*6 + kt)*64 + lane)*8];
          Bv[kt] = *(const bf8*)&wq[((ntv*6 + kt)*64 + lane)*8];
        }
#pragma unroll
        for (int mi = 0; mi < 4; ++mi) {
          int mt = wm*4 + mi;
          if (mt < MT) {
            bf8 Af[6];
#pragma unroll
            for (int kt = 0; kt < 6; ++kt)
              Af[kt] = *(const bf8*)&sm[XS0 + (mt*16+lr)*XS_S + kt*32 + lg*8];
            f4 aq = zero4, ak = zero4, av = zero4;
#pragma unroll
            for (int kt = 0; kt < 6; ++kt) {
              aq = mm(Af[kt], Bq[kt], aq);
              ak = mm(Af[kt], Bk[kt], ak);
              av = mm(Af[kt], Bv[kt], av);
            }
            const int colq = wn*16 + lr;
#pragma unroll
            for (int r = 0; r < 4; ++r) {
              int row = mt*16 + lg*4 + r;
              sm[QH0 + row*QH_S + colq] = f2b(aq[r]*0.125f);   // Q pre-scaled
              sm[KH0 + row*QH_S + colq] = f2b(ak[r]);
              sm[VT0 + colq*VT_S + row] = f2b(av[r]);          // V transposed
            }
          }
        }
        // V^T pad cols 112..127 and P pad stay zero from init (never written)
      }
      __syncthreads();

      // (B)+(C): per-wave M-tile: S = QK^T, softmax, P, O = P V (waves 0..6)
      {
        int mt = wv;
        if (mt < MT) {
          bf8 Aq[2];
#pragma unroll
          for (int ks = 0; ks < 2; ++ks)
            Aq[ks] = *(const bf8*)&sm[QH0 + (mt*16+lr)*QH_S + ks*32 + lg*8];
          f4 s[7];
#pragma unroll
          for (int kt = 0; kt < 7; ++kt) {
            f4 a = zero4;
#pragma unroll
            for (int ks = 0; ks < 2; ++ks) {
              bf8 Bk2 = *(const bf8*)&sm[KH0 + (kt*16+lr)*QH_S + ks*32 + lg*8];
              a = mm(Aq[ks], Bk2, a);
            }
            s[kt] = a;
          }
#pragma unroll
          for (int r = 0; r < 4; ++r) {
            const int row = mt*16 + lg*4 + r;
            float m = -1e30f;
#pragma unroll
            for (int kt = 0; kt < 7; ++kt) {
              float v = ((kt*16 + lr) < NTOK) ? s[kt][r] : -1e30f;
              m = fmaxf(m, v);
            }
            m = fmaxf(m, __shfl_xor(m, 1));
            m = fmaxf(m, __shfl_xor(m, 2));
            m = fmaxf(m, __shfl_xor(m, 4));
            m = fmaxf(m, __shfl_xor(m, 8));
            float p[7]; float sum = 0.f;
#pragma unroll
            for (int kt = 0; kt < 7; ++kt) {
              p[kt] = ((kt*16 + lr) < NTOK) ? __expf(s[kt][r] - m) : 0.f;
              sum += p[kt];
            }
            sum += __shfl_xor(sum, 1);
            sum += __shfl_xor(sum, 2);
            sum += __shfl_xor(sum, 4);
            sum += __shfl_xor(sum, 8);
            float inv = 1.0f / sum;
#pragma unroll
            for (int kt = 0; kt < 7; ++kt)
              sm[P0 + row*P_S + kt*16 + lr] = f2b(p[kt]*inv);
          }
          asm volatile("" ::: "memory");  // keep P writes before A-frag reads
          bf8 Ap[4];
#pragma unroll
          for (int ks = 0; ks < 4; ++ks)
            Ap[ks] = *(const bf8*)&sm[P0 + (mt*16+lr)*P_S + ks*32 + lg*8];
#pragma unroll
          for (int nt = 0; nt < 4; ++nt) {
            f4 a = zero4;
#pragma unroll
            for (int ks = 0; ks < 4; ++ks) {
              bf8 Bv2 = *(const bf8*)&sm[VT0 + (nt*16+lr)*VT_S + ks*32 + lg*8];
              a = mm(Ap[ks], Bv2, a);
            }
            const int col = nt*16 + lr;
#pragma unroll
            for (int r = 0; r < 4; ++r) {
              int row = mt*16 + lg*4 + r;
              sm[QH0 + row*QH_S + col] = f2b(a[r]);  // o_h into QH (own rows)
            }
          }
        }
      }
      __syncthreads();

      // (D) out-proj accumulate: oacc += o_h @ out_w[64h:64h+64, :]
      {
        bf8 Bo[3][2];
#pragma unroll
        for (int nt = 0; nt < 3; ++nt)
#pragma unroll
          for (int ks = 0; ks < 2; ++ks)
            Bo[nt][ks] = *(const bf8*)&wout[(size_t)(((L*12 + wn*3+nt)*6 + (h*2+ks))*64 + lane)*8];
#pragma unroll
        for (int mi = 0; mi < 4; ++mi) {
          int mt = wm*4 + mi;
          if (mt < MT) {
            bf8 Ao[2];
#pragma unroll
            for (int ks = 0; ks < 2; ++ks)
              Ao[ks] = *(const bf8*)&sm[QH0 + (mt*16+lr)*QH_S + ks*32 + lg*8];
#pragma unroll
            for (int nt = 0; nt < 3; ++nt)
#pragma unroll
              for (int ks = 0; ks < 2; ++ks)
                oacc[mi][nt] = mm(Ao[ks], Bo[nt][ks], oacc[mi][nt]);
          }
        }
      }
      __syncthreads();
    } // heads

    epilogue_ln(oacc, sm, rowred, ln1_g + L*DIMM, ln1_b + L*DIMM, out_b + L*DIMM, wm, wn, lg, lr);

    // ================= MLP =================
    f4 facc[4][3];
#pragma unroll
    for (int mi = 0; mi < 4; ++mi)
#pragma unroll
      for (int nt = 0; nt < 3; ++nt) facc[mi][nt] = zero4;

    for (int blk = 0; blk < 4; ++blk) {
      { // GEMM1 + gelu -> h_lds (QH region, stride XS_S)
        bf8 B1[3][6];
#pragma unroll
        for (int nt = 0; nt < 3; ++nt)
#pragma unroll
          for (int kt = 0; kt < 6; ++kt)
            B1[nt][kt] = *(const bf8*)&wff1[(size_t)(((L*48 + blk*12 + wn*3+nt)*6 + kt)*64 + lane)*8];
        float fb[3];
#pragma unroll
        for (int nt = 0; nt < 3; ++nt)
          fb[nt] = ff1_b[L*MLPD + blk*192 + (wn*3+nt)*16 + lr];
#pragma unroll
        for (int mi = 0; mi < 4; ++mi) {
          int mt = wm*4 + mi;
          if (mt < MT) {
            bf8 Af[6];
#pragma unroll
            for (int kt = 0; kt < 6; ++kt)
              Af[kt] = *(const bf8*)&sm[XS0 + (mt*16+lr)*XS_S + kt*32 + lg*8];
#pragma unroll
            for (int nt = 0; nt < 3; ++nt) {
              f4 a = zero4;
#pragma unroll
              for (int kt = 0; kt < 6; ++kt) a = mm(Af[kt], B1[nt][kt], a);
              int col = (wn*3+nt)*16 + lr;
#pragma unroll
              for (int r = 0; r < 4; ++r) {
                int row = mt*16 + lg*4 + r;
                sm[QH0 + row*XS_S + col] = f2b(gelu_f(a[r] + fb[nt]));
              }
            }
          }
        }
      }
      __syncthreads();
      { // GEMM2 accumulate
        bf8 B2[3][6];
#pragma unroll
        for (int nt = 0; nt < 3; ++nt)
#pragma unroll
          for (int kt = 0; kt < 6; ++kt)
            B2[nt][kt] = *(const bf8*)&wff2[(size_t)(((L*12 + wn*3+nt)*24 + blk*6 + kt)*64 + lane)*8];
#pragma unroll
        for (int mi = 0; mi < 4; ++mi) {
          int mt = wm*4 + mi;
          if (mt < MT) {
            bf8 Ah[6];
#pragma unroll
            for (int kt = 0; kt < 6; ++kt)
              Ah[kt] = *(const bf8*)&sm[QH0 + (mt*16+lr)*XS_S + kt*32 + lg*8];
#pragma unroll
            for (int nt = 0; nt < 3; ++nt)
#pragma unroll
              for (int kt = 0; kt < 6; ++kt)
                facc[mi][nt] = mm(Ah[kt], B2[nt][kt], facc[mi][nt]);
          }
        }
      }
      __syncthreads();
    }

    epilogue_ln(facc, sm, rowred, ln2_g + L*DIMM, ln2_b + L*DIMM, ff2_b + L*DIMM, wm, wn, lg, lr);
  } // layers

  // ================= head =================
  float* yv = rowred;
  if (wv == 0) {
    float x0 = b2f(sm[XS0 + lane]);
    float x1 = b2f(sm[XS0 + 64 + lane]);
    float x2 = b2f(sm[XS0 + 128 + lane]);
    float s1 = x0+x1+x2;
    float s2 = x0*x0 + x1*x1 + x2*x2;
#pragma unroll
    for (int d = 1; d < 64; d <<= 1) { s1 += __shfl_xor(s1, d); s2 += __shfl_xor(s2, d); }
    float mean = s1*(1.0f/DIMM), var = s2*(1.0f/DIMM) - mean*mean;
    float rs = rsqrtf(var + 1e-5f);
    yv[lane]      = (x0-mean)*rs*hln_g[lane]      + hln_b[lane];
    yv[64+lane]   = (x1-mean)*rs*hln_g[64+lane]   + hln_b[64+lane];
    yv[128+lane]  = (x2-mean)*rs*hln_g[128+lane]  + hln_b[128+lane];
  }
  __syncthreads();
  if (tid < NCLS) {
    float acc = head_b[tid];
    for (int k = 0; k < DIMM; ++k) acc += yv[k] * head_w[k*NCLS + tid];
    out[(size_t)b*NCLS + tid] = acc;
  }
}

extern "C" void kernel_launch(void* const* d_in, const int* in_sizes, int n_in,
                              void* d_out, int out_size, void* d_ws, size_t ws_size,
                              hipStream_t stream) {
  const float* img    = (const float*)d_in[0];
  const float* lin_w  = (const float*)d_in[1];
  const float* g_feat = (const float*)d_in[2];
  const float* pos_emb= (const float*)d_in[3];
  const float* ln1_g  = (const float*)d_in[4];
  const float* ln1_b  = (const float*)d_in[5];
  const float* ln2_g  = (const float*)d_in[6];
  const float* ln2_b  = (const float*)d_in[7];
  const float* qkv_w  = (const float*)d_in[8];
  const float* out_w  = (const float*)d_in[9];
  const float* out_b  = (const float*)d_in[10];
  const float* ff1_w  = (const float*)d_in[11];
  const float* ff1_b  = (const float*)d_in[12];
  const float* ff2_w  = (const float*)d_in[13];
  const float* ff2_b  = (const float*)d_in[14];
  const float* hln_g  = (const float*)d_in[15];
  const float* hln_b  = (const float*)d_in[16];
  const float* head_w = (const float*)d_in[17];
  const float* head_b = (const float*)d_in[18];

  u16* ws   = (u16*)d_ws;
  u16* wlin = ws;                   // 1*12*2*512    = 12288
  u16* wqkv = wlin + 12288;         // 12*36*6*512   = 1327104
  u16* wout = wqkv + 1327104;       // 12*12*6*512   = 442368
  u16* wff1 = wout + 442368;        // 12*48*6*512   = 1769472
  u16* wff2 = wff1 + 1769472;       // 12*12*24*512  = 1769472

  struct PermArgs { const float* src; u16* dst; int layers, Kdim, Ndim, realK; };
  const PermArgs pa[5] = {
    { lin_w, wlin, 1, 64, 192, 40 },
    { qkv_w, wqkv, 12, 192, 576, 192 },
    { out_w, wout, 12, 192, 192, 192 },
    { ff1_w, wff1, 12, 192, 768, 192 },
    { ff2_w, wff2, 12, 768, 192, 768 },
  };
  for (int i = 0; i < 5; ++i) {
    int total = pa[i].layers * (pa[i].Ndim/16) * (pa[i].Kdim/32) * 512;
    hipLaunchKernelGGL(permw, dim3((total + 255)/256), dim3(256), 0, stream,
                       pa[i].src, pa[i].dst, total, pa[i].Kdim/32, pa[i].Ndim/16,
                       pa[i].realK, pa[i].Ndim);
  }

  hipFuncSetAttribute(reinterpret_cast<const void*>(vit_main),
                      hipFuncAttributeMaxDynamicSharedMemorySize, SMEM_BYTES);

  hipLaunchKernelGGL(vit_main, dim3(NBATCH), dim3(512), SMEM_BYTES, stream,
                     img, g_feat, pos_emb, ln1_g, ln1_b, ln2_g, ln2_b,
                     out_b, ff1_b, ff2_b, hln_g, hln_b, head_w, head_b,
                     wlin, wqkv, wout, wff1, wff2, (float*)d_out);
}

// Round 3
// 1831.616 us; speedup vs baseline: 1.1650x; 1.0013x over previous
//
#include <hip/hip_runtime.h>

typedef unsigned short u16;

#define DIMM   192
#define DEPTH  12
#define NHEAD  3
#define DHEADD 64
#define MLPD   768
#define NCLS   35
#define NTOK   99
#define TIMG   98
#define FIMG   40
#define NBATCH 512
#define MT     7

// LDS layout (u16 element offsets)
#define XS_S 200
#define QH_S 72
#define VT_S 136
#define P_S  136
#define XS0  0
#define QH0  22400
#define KH0  30464
#define VT0  38528
#define P0   47232
#define RR_BYTE 124928
#define SMEM_BYTES 128512

typedef __attribute__((ext_vector_type(8))) __bf16 bf8;
typedef __attribute__((ext_vector_type(4))) float  f4;

__device__ __forceinline__ float b2f(u16 u){
  union { float f; unsigned u; } v; v.u = ((unsigned)u) << 16; return v.f;
}
__device__ __forceinline__ u16 f2b(float f){
  union { float f; unsigned u; } v; v.f = f;
  unsigned r = v.u + 0x7FFFu + ((v.u >> 16) & 1u);
  return (u16)(r >> 16);
}
__device__ __forceinline__ f4 mm(bf8 a, bf8 b, f4 c){
  return __builtin_amdgcn_mfma_f32_16x16x32_bf16(a, b, c, 0, 0, 0);
}
__device__ __forceinline__ float gelu_f(float x){
  float z = x * 0.7071067811865476f;
  float az = fabsf(z);
  float t = 1.0f / (1.0f + 0.3275911f * az);
  float poly = ((((1.061405429f*t - 1.453152027f)*t + 1.421413741f)*t
                 - 0.284496736f)*t + 0.254829592f)*t;
  float erfv = 1.0f - poly * __expf(-az*az);
  erfv = (z < 0.0f) ? -erfv : erfv;
  return 0.5f * x * (1.0f + erfv);
}

// Pre-permute weights: f32 [layers][K][N] -> bf16 fragment order
extern "C" __global__ void permw(const float* __restrict__ src, u16* __restrict__ dst,
                                 int total, int KT, int NT, int realK, int Ndim){
  int i = blockIdx.x * 256 + threadIdx.x;
  if (i >= total) return;
  int j = i & 7, l = (i >> 3) & 63;
  int rest = i >> 9;
  int kt = rest % KT; rest /= KT;
  int nt = rest % NT; int layer = rest / NT;
  int k = kt*32 + (l>>4)*8 + j;
  int n = nt*16 + (l&15);
  float v = (k < realK) ? src[((size_t)layer*realK + k)*Ndim + n] : 0.0f;
  dst[i] = f2b(v);
}

// 8-wave epilogue: waves = 2 M-groups (wm) x 4 N-groups (wn)
__device__ __forceinline__ void epilogue_ln(
    f4 (&acc)[4][3], u16* sm, float* rowred,
    const float* gptr, const float* bptr, const float* biasptr,
    int wm, int wn, int lg, int lr)
{
  float gg[3], bb[3], ob[3];
#pragma unroll
  for (int nt = 0; nt < 3; ++nt) {
    int c = wn*48 + nt*16 + lr;
    gg[nt] = gptr[c]; bb[nt] = bptr[c]; ob[nt] = biasptr[c];
  }
#pragma unroll
  for (int mi = 0; mi < 4; ++mi) {
    int mt = wm*4 + mi;
    if (mt < MT) {
#pragma unroll
      for (int r = 0; r < 4; ++r) {
        int row = mt*16 + lg*4 + r;
        float s1 = 0.f, s2 = 0.f;
#pragma unroll
        for (int nt = 0; nt < 3; ++nt) {
          int c = wn*48 + nt*16 + lr;
          float v = acc[mi][nt][r] + ob[nt] + b2f(sm[XS0 + row*XS_S + c]);
          acc[mi][nt][r] = v;
          s1 += v; s2 += v*v;
        }
        s1 += __shfl_xor(s1,1); s2 += __shfl_xor(s2,1);
        s1 += __shfl_xor(s1,2); s2 += __shfl_xor(s2,2);
        s1 += __shfl_xor(s1,4); s2 += __shfl_xor(s2,4);
        s1 += __shfl_xor(s1,8); s2 += __shfl_xor(s2,8);
        if (lr == 0) {
          rowred[(row*4 + wn)*2 + 0] = s1;
          rowred[(row*4 + wn)*2 + 1] = s2;
        }
      }
    }
  }
  __syncthreads();
#pragma unroll
  for (int mi = 0; mi < 4; ++mi) {
    int mt = wm*4 + mi;
    if (mt < MT) {
#pragma unroll
      for (int r = 0; r < 4; ++r) {
        int row = mt*16 + lg*4 + r;
        float S1 = rowred[row*8+0]+rowred[row*8+2]+rowred[row*8+4]+rowred[row*8+6];
        float S2 = rowred[row*8+1]+rowred[row*8+3]+rowred[row*8+5]+rowred[row*8+7];
        float mean = S1 * (1.0f/DIMM);
        float var  = S2 * (1.0f/DIMM) - mean*mean;
        float rs = rsqrtf(var + 1e-5f);
        if (row < NTOK) {
#pragma unroll
          for (int nt = 0; nt < 3; ++nt) {
            int c = wn*48 + nt*16 + lr;
            float y = (acc[mi][nt][r] - mean)*rs*gg[nt] + bb[nt];
            sm[XS0 + row*XS_S + c] = f2b(y);
          }
        }
      }
    }
  }
  __syncthreads();
}

extern "C" __global__ __launch_bounds__(512, 2) void vit_main(
    const float* __restrict__ img,   const float* __restrict__ g_feat,
    const float* __restrict__ pos_emb,
    const float* __restrict__ ln1_g, const float* __restrict__ ln1_b,
    const float* __restrict__ ln2_g, const float* __restrict__ ln2_b,
    const float* __restrict__ out_b, const float* __restrict__ ff1_b,
    const float* __restrict__ ff2_b,
    const float* __restrict__ hln_g, const float* __restrict__ hln_b,
    const float* __restrict__ head_w, const float* __restrict__ head_b,
    const u16* __restrict__ wlin, const u16* __restrict__ wqkv,
    const u16* __restrict__ wout, const u16* __restrict__ wff1,
    const u16* __restrict__ wff2,
    float* __restrict__ out)
{
  extern __shared__ __align__(16) u16 sm[];
  float* rowred = (float*)((char*)sm + RR_BYTE);
  const int tid  = threadIdx.x;
  const int lane = tid & 63;
  const int wv   = tid >> 6;     // 0..7
  const int wm   = wv >> 2;      // M-group: rows wm*64..
  const int wn   = wv & 3;       // N-group: cols wn*48..
  const int lg   = lane >> 4;
  const int lr   = lane & 15;
  const int b    = blockIdx.x;

  // zero all LDS once (pad regions must stay 0 forever)
  for (int i = tid; i < SMEM_BYTES/4; i += 512) ((unsigned*)sm)[i] = 0u;
  __syncthreads();

  // ---- patch embed: stage img (shifted +1 row; row0 = cls slot) into QH region ----
  const float* imgb = img + (size_t)b * (TIMG*FIMG);
  for (int i = tid; i < TIMG*FIMG; i += 512) {
    int r = i / FIMG, c = i - r*FIMG;
    sm[QH0 + (r+1)*QH_S + c] = f2b(imgb[i]);
  }
  __syncthreads();
  {
    bf8 Bf[3][2];
#pragma unroll
    for (int nt = 0; nt < 3; ++nt)
#pragma unroll
      for (int kt = 0; kt < 2; ++kt)
        Bf[nt][kt] = *(const bf8*)&wlin[(((wn*3+nt)*2 + kt)*64 + lane)*8];
#pragma unroll
    for (int mi = 0; mi < 4; ++mi) {
      int mt = wm*4 + mi;
      if (mt < MT) {
        bf8 Af[2];
#pragma unroll
        for (int kt = 0; kt < 2; ++kt)
          Af[kt] = *(const bf8*)&sm[QH0 + (mt*16+lr)*QH_S + kt*32 + lg*8];
#pragma unroll
        for (int nt = 0; nt < 3; ++nt) {
          f4 a = {0.f,0.f,0.f,0.f};
#pragma unroll
          for (int kt = 0; kt < 2; ++kt) a = mm(Af[kt], Bf[nt][kt], a);
          int col = (wn*3+nt)*16 + lr;
#pragma unroll
          for (int r = 0; r < 4; ++r) {
            int row = mt*16 + lg*4 + r;
            if (row < NTOK) {
              float v = a[r] + pos_emb[row*DIMM + col] + (row==0 ? g_feat[col] : 0.f);
              sm[XS0 + row*XS_S + col] = f2b(v);
            }
          }
        }
      }
    }
  }
  __syncthreads();

  const f4 zero4 = {0.f,0.f,0.f,0.f};

  for (int L = 0; L < DEPTH; ++L) {
    // ================= attention =================
    f4 oacc[4][3];
#pragma unroll
    for (int mi = 0; mi < 4; ++mi)
#pragma unroll
      for (int nt = 0; nt < 3; ++nt) oacc[mi][nt] = zero4;

    for (int h = 0; h < NHEAD; ++h) {
      // (A) qkv GEMM: wave (wm,wn) does q/k/v N-subtile wn, M-group wm
      {
        const u16* wq = wqkv + (size_t)L*36*6*512;
        const int ntq = h*4 + wn, ntk = 12 + h*4 + wn, ntv = 24 + h*4 + wn;
        bf8 Bq[6], Bk[6], Bv[6];
#pragma unroll
        for (int kt = 0; kt < 6; ++kt) {
          Bq[kt] = *(const bf8*)&wq[((ntq*6 + kt)*64 + lane)*8];
          Bk[kt] = *(const bf8*)&wq[((ntk*6 + kt)*64 + lane)*8];
          Bv[kt] = *(const bf8*)&wq[((ntv*6 + kt)*64 + lane)*8];
        }
#pragma unroll
        for (int mi = 0; mi < 4; ++mi) {
          int mt = wm*4 + mi;
          if (mt < MT) {
            bf8 Af[6];
#pragma unroll
            for (int kt = 0; kt < 6; ++kt)
              Af[kt] = *(const bf8*)&sm[XS0 + (mt*16+lr)*XS_S + kt*32 + lg*8];
            f4 aq = zero4, ak = zero4, av = zero4;
#pragma unroll
            for (int kt = 0; kt < 6; ++kt) {
              aq = mm(Af[kt], Bq[kt], aq);
              ak = mm(Af[kt], Bk[kt], ak);
              av = mm(Af[kt], Bv[kt], av);
            }
            const int colq = wn*16 + lr;
#pragma unroll
            for (int r = 0; r < 4; ++r) {
              int row = mt*16 + lg*4 + r;
              sm[QH0 + row*QH_S + colq] = f2b(aq[r]*0.125f);   // Q pre-scaled
              sm[KH0 + row*QH_S + colq] = f2b(ak[r]);
              sm[VT0 + colq*VT_S + row] = f2b(av[r]);          // V transposed
            }
          }
        }
        // V^T pad cols 112..127 and P pad stay zero from init (never written)
      }
      __syncthreads();

      // (B)+(C): per-wave M-tile: S = QK^T, softmax, P, O = P V (waves 0..6)
      {
        int mt = wv;
        if (mt < MT) {
          bf8 Aq[2];
#pragma unroll
          for (int ks = 0; ks < 2; ++ks)
            Aq[ks] = *(const bf8*)&sm[QH0 + (mt*16+lr)*QH_S + ks*32 + lg*8];
          f4 s[7];
#pragma unroll
          for (int kt = 0; kt < 7; ++kt) {
            f4 a = zero4;
#pragma unroll
            for (int ks = 0; ks < 2; ++ks) {
              bf8 Bk2 = *(const bf8*)&sm[KH0 + (kt*16+lr)*QH_S + ks*32 + lg*8];
              a = mm(Aq[ks], Bk2, a);
            }
            s[kt] = a;
          }
#pragma unroll
          for (int r = 0; r < 4; ++r) {
            const int row = mt*16 + lg*4 + r;
            float m = -1e30f;
#pragma unroll
            for (int kt = 0; kt < 7; ++kt) {
              float v = ((kt*16 + lr) < NTOK) ? s[kt][r] : -1e30f;
              m = fmaxf(m, v);
            }
            m = fmaxf(m, __shfl_xor(m, 1));
            m = fmaxf(m, __shfl_xor(m, 2));
            m = fmaxf(m, __shfl_xor(m, 4));
            m = fmaxf(m, __shfl_xor(m, 8));
            float p[7]; float sum = 0.f;
#pragma unroll
            for (int kt = 0; kt < 7; ++kt) {
              p[kt] = ((kt*16 + lr) < NTOK) ? __expf(s[kt][r] - m) : 0.f;
              sum += p[kt];
            }
            sum += __shfl_xor(sum, 1);
            sum += __shfl_xor(sum, 2);
            sum += __shfl_xor(sum, 4);
            sum += __shfl_xor(sum, 8);
            float inv = 1.0f / sum;
#pragma unroll
            for (int kt = 0; kt < 7; ++kt)
              sm[P0 + row*P_S + kt*16 + lr] = f2b(p[kt]*inv);
          }
          asm volatile("" ::: "memory");  // keep P writes before A-frag reads
          bf8 Ap[4];
#pragma unroll
          for (int ks = 0; ks < 4; ++ks)
            Ap[ks] = *(const bf8*)&sm[P0 + (mt*16+lr)*P_S + ks*32 + lg*8];
#pragma unroll
          for (int nt = 0; nt < 4; ++nt) {
            f4 a = zero4;
#pragma unroll
            for (int ks = 0; ks < 4; ++ks) {
              bf8 Bv2 = *(const bf8*)&sm[VT0 + (nt*16+lr)*VT_S + ks*32 + lg*8];
              a = mm(Ap[ks], Bv2, a);
            }
            const int col = nt*16 + lr;
#pragma unroll
            for (int r = 0; r < 4; ++r) {
              int row = mt*16 + lg*4 + r;
              sm[QH0 + row*QH_S + col] = f2b(a[r]);  // o_h into QH (own rows)
            }
          }
        }
      }
      __syncthreads();

      // (D) out-proj accumulate: oacc += o_h @ out_w[64h:64h+64, :]
      {
        bf8 Bo[3][2];
#pragma unroll
        for (int nt = 0; nt < 3; ++nt)
#pragma unroll
          for (int ks = 0; ks < 2; ++ks)
            Bo[nt][ks] = *(const bf8*)&wout[(size_t)(((L*12 + wn*3+nt)*6 + (h*2+ks))*64 + lane)*8];
#pragma unroll
        for (int mi = 0; mi < 4; ++mi) {
          int mt = wm*4 + mi;
          if (mt < MT) {
            bf8 Ao[2];
#pragma unroll
            for (int ks = 0; ks < 2; ++ks)
              Ao[ks] = *(const bf8*)&sm[QH0 + (mt*16+lr)*QH_S + ks*32 + lg*8];
#pragma unroll
            for (int nt = 0; nt < 3; ++nt)
#pragma unroll
              for (int ks = 0; ks < 2; ++ks)
                oacc[mi][nt] = mm(Ao[ks], Bo[nt][ks], oacc[mi][nt]);
          }
        }
      }
      __syncthreads();
    } // heads

    epilogue_ln(oacc, sm, rowred, ln1_g + L*DIMM, ln1_b + L*DIMM, out_b + L*DIMM, wm, wn, lg, lr);

    // ================= MLP =================
    f4 facc[4][3];
#pragma unroll
    for (int mi = 0; mi < 4; ++mi)
#pragma unroll
      for (int nt = 0; nt < 3; ++nt) facc[mi][nt] = zero4;

    for (int blk = 0; blk < 4; ++blk) {
      { // GEMM1 + gelu -> h_lds (QH region, stride XS_S)
        bf8 B1[3][6];
#pragma unroll
        for (int nt = 0; nt < 3; ++nt)
#pragma unroll
          for (int kt = 0; kt < 6; ++kt)
            B1[nt][kt] = *(const bf8*)&wff1[(size_t)(((L*48 + blk*12 + wn*3+nt)*6 + kt)*64 + lane)*8];
        float fb[3];
#pragma unroll
        for (int nt = 0; nt < 3; ++nt)
          fb[nt] = ff1_b[L*MLPD + blk*192 + (wn*3+nt)*16 + lr];
#pragma unroll
        for (int mi = 0; mi < 4; ++mi) {
          int mt = wm*4 + mi;
          if (mt < MT) {
            bf8 Af[6];
#pragma unroll
            for (int kt = 0; kt < 6; ++kt)
              Af[kt] = *(const bf8*)&sm[XS0 + (mt*16+lr)*XS_S + kt*32 + lg*8];
#pragma unroll
            for (int nt = 0; nt < 3; ++nt) {
              f4 a = zero4;
#pragma unroll
              for (int kt = 0; kt < 6; ++kt) a = mm(Af[kt], B1[nt][kt], a);
              int col = (wn*3+nt)*16 + lr;
#pragma unroll
              for (int r = 0; r < 4; ++r) {
                int row = mt*16 + lg*4 + r;
                sm[QH0 + row*XS_S + col] = f2b(gelu_f(a[r] + fb[nt]));
              }
            }
          }
        }
      }
      __syncthreads();
      { // GEMM2 accumulate
        bf8 B2[3][6];
#pragma unroll
        for (int nt = 0; nt < 3; ++nt)
#pragma unroll
          for (int kt = 0; kt < 6; ++kt)
            B2[nt][kt] = *(const bf8*)&wff2[(size_t)(((L*12 + wn*3+nt)*24 + blk*6 + kt)*64 + lane)*8];
#pragma unroll
        for (int mi = 0; mi < 4; ++mi) {
          int mt = wm*4 + mi;
          if (mt < MT) {
            bf8 Ah[6];
#pragma unroll
            for (int kt = 0; kt < 6; ++kt)
              Ah[kt] = *(const bf8*)&sm[QH0 + (mt*16+lr)*XS_S + kt*32 + lg*8];
#pragma unroll
            for (int nt = 0; nt < 3; ++nt)
#pragma unroll
              for (int kt = 0; kt < 6; ++kt)
                facc[mi][nt] = mm(Ah[kt], B2[nt][kt], facc[mi][nt]);
          }
        }
      }
      __syncthreads();
    }

    epilogue_ln(facc, sm, rowred, ln2_g + L*DIMM, ln2_b + L*DIMM, ff2_b + L*DIMM, wm, wn, lg, lr);
  } // layers

  // ================= head =================
  float* yv = rowred;
  if (wv == 0) {
    float x0 = b2f(sm[XS0 + lane]);
    float x1 = b2f(sm[XS0 + 64 + lane]);
    float x2 = b2f(sm[XS0 + 128 + lane]);
    float s1 = x0+x1+x2;
    float s2 = x0*x0 + x1*x1 + x2*x2;
#pragma unroll
    for (int d = 1; d < 64; d <<= 1) { s1 += __shfl_xor(s1, d); s2 += __shfl_xor(s2, d); }
    float mean = s1*(1.0f/DIMM), var = s2*(1.0f/DIMM) - mean*mean;
    float rs = rsqrtf(var + 1e-5f);
    yv[lane]      = (x0-mean)*rs*hln_g[lane]      + hln_b[lane];
    yv[64+lane]   = (x1-mean)*rs*hln_g[64+lane]   + hln_b[64+lane];
    yv[128+lane]  = (x2-mean)*rs*hln_g[128+lane]  + hln_b[128+lane];
  }
  __syncthreads();
  if (tid < NCLS) {
    float acc = head_b[tid];
    for (int k = 0; k < DIMM; ++k) acc += yv[k] * head_w[k*NCLS + tid];
    out[(size_t)b*NCLS + tid] = acc;
  }
}

extern "C" void kernel_launch(void* const* d_in, const int* in_sizes, int n_in,
                              void* d_out, int out_size, void* d_ws, size_t ws_size,
                              hipStream_t stream) {
  const float* img    = (const float*)d_in[0];
  const float* lin_w  = (const float*)d_in[1];
  const float* g_feat = (const float*)d_in[2];
  const float* pos_emb= (const float*)d_in[3];
  const float* ln1_g  = (const float*)d_in[4];
  const float* ln1_b  = (const float*)d_in[5];
  const float* ln2_g  = (const float*)d_in[6];
  const float* ln2_b  = (const float*)d_in[7];
  const float* qkv_w  = (const float*)d_in[8];
  const float* out_w  = (const float*)d_in[9];
  const float* out_b  = (const float*)d_in[10];
  const float* ff1_w  = (const float*)d_in[11];
  const float* ff1_b  = (const float*)d_in[12];
  const float* ff2_w  = (const float*)d_in[13];
  const float* ff2_b  = (const float*)d_in[14];
  const float* hln_g  = (const float*)d_in[15];
  const float* hln_b  = (const float*)d_in[16];
  const float* head_w = (const float*)d_in[17];
  const float* head_b = (const float*)d_in[18];

  u16* ws   = (u16*)d_ws;
  u16* wlin = ws;                   // 1*12*2*512    = 12288
  u16* wqkv = wlin + 12288;         // 12*36*6*512   = 1327104
  u16* wout = wqkv + 1327104;       // 12*12*6*512   = 442368
  u16* wff1 = wout + 442368;        // 12*48*6*512   = 1769472
  u16* wff2 = wff1 + 1769472;       // 12*12*24*512  = 1769472

  struct PermArgs { const float* src; u16* dst; int layers, Kdim, Ndim, realK; };
  const PermArgs pa[5] = {
    { lin_w, wlin, 1, 64, 192, 40 },
    { qkv_w, wqkv, 12, 192, 576, 192 },
    { out_w, wout, 12, 192, 192, 192 },
    { ff1_w, wff1, 12, 192, 768, 192 },
    { ff2_w, wff2, 12, 768, 192, 768 },
  };
  for (int i = 0; i < 5; ++i) {
    int total = pa[i].layers * (pa[i].Ndim/16) * (pa[i].Kdim/32) * 512;
    hipLaunchKernelGGL(permw, dim3((total + 255)/256), dim3(256), 0, stream,
                       pa[i].src, pa[i].dst, total, pa[i].Kdim/32, pa[i].Ndim/16,
                       pa[i].realK, pa[i].Ndim);
  }

  hipFuncSetAttribute(reinterpret_cast<const void*>(vit_main),
                      hipFuncAttributeMaxDynamicSharedMemorySize, SMEM_BYTES);

  hipLaunchKernelGGL(vit_main, dim3(NBATCH), dim3(512), SMEM_BYTES, stream,
                     img, g_feat, pos_emb, ln1_g, ln1_b, ln2_g, ln2_b,
                     out_b, ff1_b, ff2_b, hln_g, hln_b, head_w, head_b,
                     wlin, wqkv, wout, wff1, wff2, (float*)d_out);
}

// Round 4
// 1766.841 us; speedup vs baseline: 1.2077x; 1.0367x over previous
//
#include <hip/hip_runtime.h>

typedef unsigned short u16;

#define DIMM   192
#define DEPTH  12
#define NHEAD  3
#define DHEADD 64
#define MLPD   768
#define NCLS   35
#define NTOK   99
#define TIMG   98
#define FIMG   40
#define NBATCH 512
#define MT     7

// LDS layout (u16 element offsets)
#define XS_S 200
#define QH_S 72
#define VT_S 136
#define P_S  136
#define XS0  0
#define QH0  22400
#define KH0  30464
#define VT0  38528
#define P0   47232
#define RR_BYTE 124928
#define SMEM_BYTES 128512

typedef __attribute__((ext_vector_type(8))) __bf16 bf8;
typedef __attribute__((ext_vector_type(4))) float  f4;

__device__ __forceinline__ float b2f(u16 u){
  union { float f; unsigned u; } v; v.u = ((unsigned)u) << 16; return v.f;
}
__device__ __forceinline__ u16 f2b(float f){
  union { float f; unsigned u; } v; v.f = f;
  unsigned r = v.u + 0x7FFFu + ((v.u >> 16) & 1u);
  return (u16)(r >> 16);
}
__device__ __forceinline__ f4 mm(bf8 a, bf8 b, f4 c){
  return __builtin_amdgcn_mfma_f32_16x16x32_bf16(a, b, c, 0, 0, 0);
}
__device__ __forceinline__ float gelu_f(float x){
  float z = x * 0.7071067811865476f;
  float az = fabsf(z);
  float t = 1.0f / (1.0f + 0.3275911f * az);
  float poly = ((((1.061405429f*t - 1.453152027f)*t + 1.421413741f)*t
                 - 0.284496736f)*t + 0.254829592f)*t;
  float erfv = 1.0f - poly * __expf(-az*az);
  erfv = (z < 0.0f) ? -erfv : erfv;
  return 0.5f * x * (1.0f + erfv);
}

// Pre-permute weights: f32 [layers][K][N] -> bf16 fragment order
extern "C" __global__ void permw(const float* __restrict__ src, u16* __restrict__ dst,
                                 int total, int KT, int NT, int realK, int Ndim){
  int i = blockIdx.x * 256 + threadIdx.x;
  if (i >= total) return;
  int j = i & 7, l = (i >> 3) & 63;
  int rest = i >> 9;
  int kt = rest % KT; rest /= KT;
  int nt = rest % NT; int layer = rest / NT;
  int k = kt*32 + (l>>4)*8 + j;
  int n = nt*16 + (l&15);
  float v = (k < realK) ? src[((size_t)layer*realK + k)*Ndim + n] : 0.0f;
  dst[i] = f2b(v);
}

// 8-wave epilogue: waves = 2 M-groups (wm) x 4 N-groups (wn)
__device__ __forceinline__ void epilogue_ln(
    f4 (&acc)[4][3], u16* sm, float* rowred,
    const float* gptr, const float* bptr, const float* biasptr,
    int wm, int wn, int lg, int lr)
{
  float gg[3], bb[3], ob[3];
#pragma unroll
  for (int nt = 0; nt < 3; ++nt) {
    int c = wn*48 + nt*16 + lr;
    gg[nt] = gptr[c]; bb[nt] = bptr[c]; ob[nt] = biasptr[c];
  }
#pragma unroll
  for (int mi = 0; mi < 4; ++mi) {
    int mt = wm*4 + mi;
    if (mt < MT) {
#pragma unroll
      for (int r = 0; r < 4; ++r) {
        int row = mt*16 + lg*4 + r;
        float s1 = 0.f, s2 = 0.f;
#pragma unroll
        for (int nt = 0; nt < 3; ++nt) {
          int c = wn*48 + nt*16 + lr;
          float v = acc[mi][nt][r] + ob[nt] + b2f(sm[XS0 + row*XS_S + c]);
          acc[mi][nt][r] = v;
          s1 += v; s2 += v*v;
        }
        s1 += __shfl_xor(s1,1); s2 += __shfl_xor(s2,1);
        s1 += __shfl_xor(s1,2); s2 += __shfl_xor(s2,2);
        s1 += __shfl_xor(s1,4); s2 += __shfl_xor(s2,4);
        s1 += __shfl_xor(s1,8); s2 += __shfl_xor(s2,8);
        if (lr == 0) {
          rowred[(row*4 + wn)*2 + 0] = s1;
          rowred[(row*4 + wn)*2 + 1] = s2;
        }
      }
    }
  }
  __syncthreads();
#pragma unroll
  for (int mi = 0; mi < 4; ++mi) {
    int mt = wm*4 + mi;
    if (mt < MT) {
#pragma unroll
      for (int r = 0; r < 4; ++r) {
        int row = mt*16 + lg*4 + r;
        float S1 = rowred[row*8+0]+rowred[row*8+2]+rowred[row*8+4]+rowred[row*8+6];
        float S2 = rowred[row*8+1]+rowred[row*8+3]+rowred[row*8+5]+rowred[row*8+7];
        float mean = S1 * (1.0f/DIMM);
        float var  = S2 * (1.0f/DIMM) - mean*mean;
        float rs = rsqrtf(var + 1e-5f);
        if (row < NTOK) {
#pragma unroll
          for (int nt = 0; nt < 3; ++nt) {
            int c = wn*48 + nt*16 + lr;
            float y = (acc[mi][nt][r] - mean)*rs*gg[nt] + bb[nt];
            sm[XS0 + row*XS_S + c] = f2b(y);
          }
        }
      }
    }
  }
  __syncthreads();
}

extern "C" __global__
__attribute__((amdgpu_flat_work_group_size(512,512), amdgpu_waves_per_eu(2,2)))
void vit_main(
    const float* __restrict__ img,   const float* __restrict__ g_feat,
    const float* __restrict__ pos_emb,
    const float* __restrict__ ln1_g, const float* __restrict__ ln1_b,
    const float* __restrict__ ln2_g, const float* __restrict__ ln2_b,
    const float* __restrict__ out_b, const float* __restrict__ ff1_b,
    const float* __restrict__ ff2_b,
    const float* __restrict__ hln_g, const float* __restrict__ hln_b,
    const float* __restrict__ head_w, const float* __restrict__ head_b,
    const u16* __restrict__ wlin, const u16* __restrict__ wqkv,
    const u16* __restrict__ wout, const u16* __restrict__ wff1,
    const u16* __restrict__ wff2,
    float* __restrict__ out)
{
  extern __shared__ __align__(16) u16 sm[];
  float* rowred = (float*)((char*)sm + RR_BYTE);
  const int tid  = threadIdx.x;
  const int lane = tid & 63;
  const int wv   = tid >> 6;     // 0..7
  const int wm   = wv >> 2;      // M-group: rows wm*64..
  const int wn   = wv & 3;       // N-group: cols wn*48..
  const int lg   = lane >> 4;
  const int lr   = lane & 15;
  const int b    = blockIdx.x;

  // zero all LDS once (pad regions must stay 0 forever)
  for (int i = tid; i < SMEM_BYTES/4; i += 512) ((unsigned*)sm)[i] = 0u;
  __syncthreads();

  // ---- patch embed: stage img (shifted +1 row; row0 = cls slot) into QH region ----
  const float* imgb = img + (size_t)b * (TIMG*FIMG);
  for (int i = tid; i < TIMG*FIMG; i += 512) {
    int r = i / FIMG, c = i - r*FIMG;
    sm[QH0 + (r+1)*QH_S + c] = f2b(imgb[i]);
  }
  __syncthreads();
  {
    bf8 Bf[3][2];
#pragma unroll
    for (int nt = 0; nt < 3; ++nt)
#pragma unroll
      for (int kt = 0; kt < 2; ++kt)
        Bf[nt][kt] = *(const bf8*)&wlin[(((wn*3+nt)*2 + kt)*64 + lane)*8];
#pragma unroll
    for (int mi = 0; mi < 4; ++mi) {
      int mt = wm*4 + mi;
      if (mt < MT) {
        bf8 Af[2];
#pragma unroll
        for (int kt = 0; kt < 2; ++kt)
          Af[kt] = *(const bf8*)&sm[QH0 + (mt*16+lr)*QH_S + kt*32 + lg*8];
#pragma unroll
        for (int nt = 0; nt < 3; ++nt) {
          f4 a = {0.f,0.f,0.f,0.f};
#pragma unroll
          for (int kt = 0; kt < 2; ++kt) a = mm(Af[kt], Bf[nt][kt], a);
          int col = (wn*3+nt)*16 + lr;
#pragma unroll
          for (int r = 0; r < 4; ++r) {
            int row = mt*16 + lg*4 + r;
            if (row < NTOK) {
              float v = a[r] + pos_emb[row*DIMM + col] + (row==0 ? g_feat[col] : 0.f);
              sm[XS0 + row*XS_S + col] = f2b(v);
            }
          }
        }
      }
    }
  }
  __syncthreads();

  const f4 zero4 = {0.f,0.f,0.f,0.f};

  for (int L = 0; L < DEPTH; ++L) {
    // ================= attention =================
    f4 oacc[4][3];
#pragma unroll
    for (int mi = 0; mi < 4; ++mi)
#pragma unroll
      for (int nt = 0; nt < 3; ++nt) oacc[mi][nt] = zero4;

    for (int h = 0; h < NHEAD; ++h) {
      // (A) qkv GEMM: wave (wm,wn) does q/k/v N-subtile wn, M-group wm
      {
        const u16* wq = wqkv + (size_t)L*36*6*512;
        const int ntq = h*4 + wn, ntk = 12 + h*4 + wn, ntv = 24 + h*4 + wn;
        bf8 Bq[6], Bk[6], Bv[6];
#pragma unroll
        for (int kt = 0; kt < 6; ++kt) {
          Bq[kt] = *(const bf8*)&wq[((ntq*6 + kt)*64 + lane)*8];
          Bk[kt] = *(const bf8*)&wq[((ntk*6 + kt)*64 + lane)*8];
          Bv[kt] = *(const bf8*)&wq[((ntv*6 + kt)*64 + lane)*8];
        }
#pragma unroll
        for (int mi = 0; mi < 4; ++mi) {
          int mt = wm*4 + mi;
          if (mt < MT) {
            bf8 Af[6];
#pragma unroll
            for (int kt = 0; kt < 6; ++kt)
              Af[kt] = *(const bf8*)&sm[XS0 + (mt*16+lr)*XS_S + kt*32 + lg*8];
            f4 aq = zero4, ak = zero4, av = zero4;
#pragma unroll
            for (int kt = 0; kt < 6; ++kt) {
              aq = mm(Af[kt], Bq[kt], aq);
              ak = mm(Af[kt], Bk[kt], ak);
              av = mm(Af[kt], Bv[kt], av);
            }
            const int colq = wn*16 + lr;
#pragma unroll
            for (int r = 0; r < 4; ++r) {
              int row = mt*16 + lg*4 + r;
              sm[QH0 + row*QH_S + colq] = f2b(aq[r]*0.125f);   // Q pre-scaled
              sm[KH0 + row*QH_S + colq] = f2b(ak[r]);
              sm[VT0 + colq*VT_S + row] = f2b(av[r]);          // V transposed
            }
          }
        }
        // V^T pad cols 112..127 and P pad stay zero from init (never written)
      }
      __syncthreads();

      // (B)+(C): per-wave M-tile: S = QK^T, softmax, P, O = P V (waves 0..6)
      {
        int mt = wv;
        if (mt < MT) {
          bf8 Aq[2];
#pragma unroll
          for (int ks = 0; ks < 2; ++ks)
            Aq[ks] = *(const bf8*)&sm[QH0 + (mt*16+lr)*QH_S + ks*32 + lg*8];
          f4 s[7];
#pragma unroll
          for (int kt = 0; kt < 7; ++kt) {
            f4 a = zero4;
#pragma unroll
            for (int ks = 0; ks < 2; ++ks) {
              bf8 Bk2 = *(const bf8*)&sm[KH0 + (kt*16+lr)*QH_S + ks*32 + lg*8];
              a = mm(Aq[ks], Bk2, a);
            }
            s[kt] = a;
          }
#pragma unroll
          for (int r = 0; r < 4; ++r) {
            const int row = mt*16 + lg*4 + r;
            float m = -1e30f;
#pragma unroll
            for (int kt = 0; kt < 7; ++kt) {
              float v = ((kt*16 + lr) < NTOK) ? s[kt][r] : -1e30f;
              m = fmaxf(m, v);
            }
            m = fmaxf(m, __shfl_xor(m, 1));
            m = fmaxf(m, __shfl_xor(m, 2));
            m = fmaxf(m, __shfl_xor(m, 4));
            m = fmaxf(m, __shfl_xor(m, 8));
            float p[7]; float sum = 0.f;
#pragma unroll
            for (int kt = 0; kt < 7; ++kt) {
              p[kt] = ((kt*16 + lr) < NTOK) ? __expf(s[kt][r] - m) : 0.f;
              sum += p[kt];
            }
            sum += __shfl_xor(sum, 1);
            sum += __shfl_xor(sum, 2);
            sum += __shfl_xor(sum, 4);
            sum += __shfl_xor(sum, 8);
            float inv = 1.0f / sum;
#pragma unroll
            for (int kt = 0; kt < 7; ++kt)
              sm[P0 + row*P_S + kt*16 + lr] = f2b(p[kt]*inv);
          }
          asm volatile("" ::: "memory");  // keep P writes before A-frag reads
          bf8 Ap[4];
#pragma unroll
          for (int ks = 0; ks < 4; ++ks)
            Ap[ks] = *(const bf8*)&sm[P0 + (mt*16+lr)*P_S + ks*32 + lg*8];
#pragma unroll
          for (int nt = 0; nt < 4; ++nt) {
            f4 a = zero4;
#pragma unroll
            for (int ks = 0; ks < 4; ++ks) {
              bf8 Bv2 = *(const bf8*)&sm[VT0 + (nt*16+lr)*VT_S + ks*32 + lg*8];
              a = mm(Ap[ks], Bv2, a);
            }
            const int col = nt*16 + lr;
#pragma unroll
            for (int r = 0; r < 4; ++r) {
              int row = mt*16 + lg*4 + r;
              sm[QH0 + row*QH_S + col] = f2b(a[r]);  // o_h into QH (own rows)
            }
          }
        }
      }
      __syncthreads();

      // (D) out-proj accumulate: oacc += o_h @ out_w[64h:64h+64, :]
      {
        bf8 Bo[3][2];
#pragma unroll
        for (int nt = 0; nt < 3; ++nt)
#pragma unroll
          for (int ks = 0; ks < 2; ++ks)
            Bo[nt][ks] = *(const bf8*)&wout[(size_t)(((L*12 + wn*3+nt)*6 + (h*2+ks))*64 + lane)*8];
#pragma unroll
        for (int mi = 0; mi < 4; ++mi) {
          int mt = wm*4 + mi;
          if (mt < MT) {
            bf8 Ao[2];
#pragma unroll
            for (int ks = 0; ks < 2; ++ks)
              Ao[ks] = *(const bf8*)&sm[QH0 + (mt*16+lr)*QH_S + ks*32 + lg*8];
#pragma unroll
            for (int nt = 0; nt < 3; ++nt)
#pragma unroll
              for (int ks = 0; ks < 2; ++ks)
                oacc[mi][nt] = mm(Ao[ks], Bo[nt][ks], oacc[mi][nt]);
          }
        }
      }
      __syncthreads();
    } // heads

    epilogue_ln(oacc, sm, rowred, ln1_g + L*DIMM, ln1_b + L*DIMM, out_b + L*DIMM, wm, wn, lg, lr);

    // ================= MLP =================
    f4 facc[4][3];
#pragma unroll
    for (int mi = 0; mi < 4; ++mi)
#pragma unroll
      for (int nt = 0; nt < 3; ++nt) facc[mi][nt] = zero4;

    for (int blk = 0; blk < 4; ++blk) {
      { // GEMM1 + gelu -> h_lds (QH region, stride XS_S)
        bf8 B1[3][6];
#pragma unroll
        for (int nt = 0; nt < 3; ++nt)
#pragma unroll
          for (int kt = 0; kt < 6; ++kt)
            B1[nt][kt] = *(const bf8*)&wff1[(size_t)(((L*48 + blk*12 + wn*3+nt)*6 + kt)*64 + lane)*8];
        float fb[3];
#pragma unroll
        for (int nt = 0; nt < 3; ++nt)
          fb[nt] = ff1_b[L*MLPD + blk*192 + (wn*3+nt)*16 + lr];
#pragma unroll
        for (int mi = 0; mi < 4; ++mi) {
          int mt = wm*4 + mi;
          if (mt < MT) {
            bf8 Af[6];
#pragma unroll
            for (int kt = 0; kt < 6; ++kt)
              Af[kt] = *(const bf8*)&sm[XS0 + (mt*16+lr)*XS_S + kt*32 + lg*8];
#pragma unroll
            for (int nt = 0; nt < 3; ++nt) {
              f4 a = zero4;
#pragma unroll
              for (int kt = 0; kt < 6; ++kt) a = mm(Af[kt], B1[nt][kt], a);
              int col = (wn*3+nt)*16 + lr;
#pragma unroll
              for (int r = 0; r < 4; ++r) {
                int row = mt*16 + lg*4 + r;
                sm[QH0 + row*XS_S + col] = f2b(gelu_f(a[r] + fb[nt]));
              }
            }
          }
        }
      }
      __syncthreads();
      { // GEMM2 accumulate
        bf8 B2[3][6];
#pragma unroll
        for (int nt = 0; nt < 3; ++nt)
#pragma unroll
          for (int kt = 0; kt < 6; ++kt)
            B2[nt][kt] = *(const bf8*)&wff2[(size_t)(((L*12 + wn*3+nt)*24 + blk*6 + kt)*64 + lane)*8];
#pragma unroll
        for (int mi = 0; mi < 4; ++mi) {
          int mt = wm*4 + mi;
          if (mt < MT) {
            bf8 Ah[6];
#pragma unroll
            for (int kt = 0; kt < 6; ++kt)
              Ah[kt] = *(const bf8*)&sm[QH0 + (mt*16+lr)*XS_S + kt*32 + lg*8];
#pragma unroll
            for (int nt = 0; nt < 3; ++nt)
#pragma unroll
              for (int kt = 0; kt < 6; ++kt)
                facc[mi][nt] = mm(Ah[kt], B2[nt][kt], facc[mi][nt]);
          }
        }
      }
      __syncthreads();
    }

    epilogue_ln(facc, sm, rowred, ln2_g + L*DIMM, ln2_b + L*DIMM, ff2_b + L*DIMM, wm, wn, lg, lr);
  } // layers

  // ================= head =================
  float* yv = rowred;
  if (wv == 0) {
    float x0 = b2f(sm[XS0 + lane]);
    float x1 = b2f(sm[XS0 + 64 + lane]);
    float x2 = b2f(sm[XS0 + 128 + lane]);
    float s1 = x0+x1+x2;
    float s2 = x0*x0 + x1*x1 + x2*x2;
#pragma unroll
    for (int d = 1; d < 64; d <<= 1) { s1 += __shfl_xor(s1, d); s2 += __shfl_xor(s2, d); }
    float mean = s1*(1.0f/DIMM), var = s2*(1.0f/DIMM) - mean*mean;
    float rs = rsqrtf(var + 1e-5f);
    yv[lane]      = (x0-mean)*rs*hln_g[lane]      + hln_b[lane];
    yv[64+lane]   = (x1-mean)*rs*hln_g[64+lane]   + hln_b[64+lane];
    yv[128+lane]  = (x2-mean)*rs*hln_g[128+lane]  + hln_b[128+lane];
  }
  __syncthreads();
  if (tid < NCLS) {
    float acc = head_b[tid];
    for (int k = 0; k < DIMM; ++k) acc += yv[k] * head_w[k*NCLS + tid];
    out[(size_t)b*NCLS + tid] = acc;
  }
}

extern "C" void kernel_launch(void* const* d_in, const int* in_sizes, int n_in,
                              void* d_out, int out_size, void* d_ws, size_t ws_size,
                              hipStream_t stream) {
  const float* img    = (const float*)d_in[0];
  const float* lin_w  = (const float*)d_in[1];
  const float* g_feat = (const float*)d_in[2];
  const float* pos_emb= (const float*)d_in[3];
  const float* ln1_g  = (const float*)d_in[4];
  const float* ln1_b  = (const float*)d_in[5];
  const float* ln2_g  = (const float*)d_in[6];
  const float* ln2_b  = (const float*)d_in[7];
  const float* qkv_w  = (const float*)d_in[8];
  const float* out_w  = (const float*)d_in[9];
  const float* out_b  = (const float*)d_in[10];
  const float* ff1_w  = (const float*)d_in[11];
  const float* ff1_b  = (const float*)d_in[12];
  const float* ff2_w  = (const float*)d_in[13];
  const float* ff2_b  = (const float*)d_in[14];
  const float* hln_g  = (const float*)d_in[15];
  const float* hln_b  = (const float*)d_in[16];
  const float* head_w = (const float*)d_in[17];
  const float* head_b = (const float*)d_in[18];

  u16* ws   = (u16*)d_ws;
  u16* wlin = ws;                   // 1*12*2*512    = 12288
  u16* wqkv = wlin + 12288;         // 12*36*6*512   = 1327104
  u16* wout = wqkv + 1327104;       // 12*12*6*512   = 442368
  u16* wff1 = wout + 442368;        // 12*48*6*512   = 1769472
  u16* wff2 = wff1 + 1769472;       // 12*12*24*512  = 1769472

  struct PermArgs { const float* src; u16* dst; int layers, Kdim, Ndim, realK; };
  const PermArgs pa[5] = {
    { lin_w, wlin, 1, 64, 192, 40 },
    { qkv_w, wqkv, 12, 192, 576, 192 },
    { out_w, wout, 12, 192, 192, 192 },
    { ff1_w, wff1, 12, 192, 768, 192 },
    { ff2_w, wff2, 12, 768, 192, 768 },
  };
  for (int i = 0; i < 5; ++i) {
    int total = pa[i].layers * (pa[i].Ndim/16) * (pa[i].Kdim/32) * 512;
    hipLaunchKernelGGL(permw, dim3((total + 255)/256), dim3(256), 0, stream,
                       pa[i].src, pa[i].dst, total, pa[i].Kdim/32, pa[i].Ndim/16,
                       pa[i].realK, pa[i].Ndim);
  }

  hipFuncSetAttribute(reinterpret_cast<const void*>(vit_main),
                      hipFuncAttributeMaxDynamicSharedMemorySize, SMEM_BYTES);

  hipLaunchKernelGGL(vit_main, dim3(NBATCH), dim3(512), SMEM_BYTES, stream,
                     img, g_feat, pos_emb, ln1_g, ln1_b, ln2_g, ln2_b,
                     out_b, ff1_b, ff2_b, hln_g, hln_b, head_w, head_b,
                     wlin, wqkv, wout, wff1, wff2, (float*)d_out);
}

// Round 5
// 1619.461 us; speedup vs baseline: 1.3176x; 1.0910x over previous
//
#include <hip/hip_runtime.h>

typedef unsigned short u16;

#define DIMM   192
#define DEPTH  12
#define NHEAD  3
#define DHEADD 64
#define MLPD   768
#define NCLS   35
#define NTOK   99
#define TIMG   98
#define FIMG   40
#define NBATCH 512
#define MT     7

// LDS layout (u16 element offsets)
#define XS_S 200
#define QH_S 72
#define VT_S 136
#define P_S  136
#define XS0  0
#define QH0  22400
#define KH0  30464
#define VT0  38528
#define P0   47232
#define RR_BYTE 124928
#define SMEM_BYTES 128512

typedef __attribute__((ext_vector_type(8))) __bf16 bf8;
typedef __attribute__((ext_vector_type(4))) float  f4;

__device__ __forceinline__ float b2f(u16 u){
  union { float f; unsigned u; } v; v.u = ((unsigned)u) << 16; return v.f;
}
__device__ __forceinline__ u16 f2b(float f){
  __bf16 h = (__bf16)f;                   // native RNE convert (1 VALU op)
  union { __bf16 h; u16 u; } v; v.h = h;
  return v.u;
}
__device__ __forceinline__ f4 mm(bf8 a, bf8 b, f4 c){
  return __builtin_amdgcn_mfma_f32_16x16x32_bf16(a, b, c, 0, 0, 0);
}
__device__ __forceinline__ float gelu_f(float x){
  float z = x * 0.7071067811865476f;
  float az = fabsf(z);
  float t = 1.0f / (1.0f + 0.3275911f * az);
  float poly = ((((1.061405429f*t - 1.453152027f)*t + 1.421413741f)*t
                 - 0.284496736f)*t + 0.254829592f)*t;
  float erfv = 1.0f - poly * __expf(-az*az);
  erfv = (z < 0.0f) ? -erfv : erfv;
  return 0.5f * x * (1.0f + erfv);
}

// Pre-permute weights: f32 [layers][K][N] -> bf16 fragment order
extern "C" __global__ void permw(const float* __restrict__ src, u16* __restrict__ dst,
                                 int total, int KT, int NT, int realK, int Ndim){
  int i = blockIdx.x * 256 + threadIdx.x;
  if (i >= total) return;
  int j = i & 7, l = (i >> 3) & 63;
  int rest = i >> 9;
  int kt = rest % KT; rest /= KT;
  int nt = rest % NT; int layer = rest / NT;
  int k = kt*32 + (l>>4)*8 + j;
  int n = nt*16 + (l&15);
  float v = (k < realK) ? src[((size_t)layer*realK + k)*Ndim + n] : 0.0f;
  union { float f; unsigned u; } w; w.f = v;
  unsigned r = w.u + 0x7FFFu + ((w.u >> 16) & 1u);
  dst[i] = (u16)(r >> 16);
}

// 8-wave epilogue: waves = 2 M-groups (wm) x 4 N-groups (wn)
__device__ __forceinline__ void epilogue_ln(
    f4 (&acc)[4][3], u16* sm, float* rowred,
    const float* gptr, const float* bptr, const float* biasptr,
    int wm, int wn, int lg, int lr)
{
  float gg[3], bb[3], ob[3];
#pragma unroll
  for (int nt = 0; nt < 3; ++nt) {
    int c = wn*48 + nt*16 + lr;
    gg[nt] = gptr[c]; bb[nt] = bptr[c]; ob[nt] = biasptr[c];
  }
#pragma unroll
  for (int mi = 0; mi < 4; ++mi) {
    int mt = wm*4 + mi;
    if (mt < MT) {
#pragma unroll
      for (int r = 0; r < 4; ++r) {
        int row = mt*16 + lg*4 + r;
        float s1 = 0.f, s2 = 0.f;
#pragma unroll
        for (int nt = 0; nt < 3; ++nt) {
          int c = wn*48 + nt*16 + lr;
          float v = acc[mi][nt][r] + ob[nt] + b2f(sm[XS0 + row*XS_S + c]);
          acc[mi][nt][r] = v;
          s1 += v; s2 += v*v;
        }
        s1 += __shfl_xor(s1,1); s2 += __shfl_xor(s2,1);
        s1 += __shfl_xor(s1,2); s2 += __shfl_xor(s2,2);
        s1 += __shfl_xor(s1,4); s2 += __shfl_xor(s2,4);
        s1 += __shfl_xor(s1,8); s2 += __shfl_xor(s2,8);
        if (lr == 0) {
          rowred[(row*4 + wn)*2 + 0] = s1;
          rowred[(row*4 + wn)*2 + 1] = s2;
        }
      }
    }
  }
  __syncthreads();
#pragma unroll
  for (int mi = 0; mi < 4; ++mi) {
    int mt = wm*4 + mi;
    if (mt < MT) {
#pragma unroll
      for (int r = 0; r < 4; ++r) {
        int row = mt*16 + lg*4 + r;
        float S1 = rowred[row*8+0]+rowred[row*8+2]+rowred[row*8+4]+rowred[row*8+6];
        float S2 = rowred[row*8+1]+rowred[row*8+3]+rowred[row*8+5]+rowred[row*8+7];
        float mean = S1 * (1.0f/DIMM);
        float var  = S2 * (1.0f/DIMM) - mean*mean;
        float rs = rsqrtf(var + 1e-5f);
        if (row < NTOK) {
#pragma unroll
          for (int nt = 0; nt < 3; ++nt) {
            int c = wn*48 + nt*16 + lr;
            float y = (acc[mi][nt][r] - mean)*rs*gg[nt] + bb[nt];
            sm[XS0 + row*XS_S + c] = f2b(y);
          }
        }
      }
    }
  }
  __syncthreads();
}

extern "C" __global__
__attribute__((amdgpu_flat_work_group_size(512,512), amdgpu_waves_per_eu(2,2)))
void vit_main(
    const float* __restrict__ img,   const float* __restrict__ g_feat,
    const float* __restrict__ pos_emb,
    const float* __restrict__ ln1_g, const float* __restrict__ ln1_b,
    const float* __restrict__ ln2_g, const float* __restrict__ ln2_b,
    const float* __restrict__ out_b, const float* __restrict__ ff1_b,
    const float* __restrict__ ff2_b,
    const float* __restrict__ hln_g, const float* __restrict__ hln_b,
    const float* __restrict__ head_w, const float* __restrict__ head_b,
    const u16* __restrict__ wlin, const u16* __restrict__ wqkv,
    const u16* __restrict__ wout, const u16* __restrict__ wff1,
    const u16* __restrict__ wff2,
    float* __restrict__ out)
{
  extern __shared__ __align__(16) u16 sm[];
  float* rowred = (float*)((char*)sm + RR_BYTE);
  const int tid  = threadIdx.x;
  const int lane = tid & 63;
  const int wv   = tid >> 6;     // 0..7
  const int wm   = wv >> 2;      // M-group: rows wm*64..
  const int wn   = wv & 3;       // N-group: cols wn*48..
  const int lg   = lane >> 4;
  const int lr   = lane & 15;
  const int b    = blockIdx.x;

  // zero all LDS once (pad regions must stay 0 forever)
  for (int i = tid; i < SMEM_BYTES/4; i += 512) ((unsigned*)sm)[i] = 0u;
  __syncthreads();

  // ---- patch embed: stage img (shifted +1 row; row0 = cls slot) into QH region ----
  const float* imgb = img + (size_t)b * (TIMG*FIMG);
  for (int i = tid; i < TIMG*FIMG; i += 512) {
    int r = i / FIMG, c = i - r*FIMG;
    sm[QH0 + (r+1)*QH_S + c] = f2b(imgb[i]);
  }
  __syncthreads();
  {
    bf8 Bf[3][2];
#pragma unroll
    for (int nt = 0; nt < 3; ++nt)
#pragma unroll
      for (int kt = 0; kt < 2; ++kt)
        Bf[nt][kt] = *(const bf8*)&wlin[(((wn*3+nt)*2 + kt)*64 + lane)*8];
#pragma unroll
    for (int mi = 0; mi < 4; ++mi) {
      int mt = wm*4 + mi;
      if (mt < MT) {
        bf8 Af[2];
#pragma unroll
        for (int kt = 0; kt < 2; ++kt)
          Af[kt] = *(const bf8*)&sm[QH0 + (mt*16+lr)*QH_S + kt*32 + lg*8];
#pragma unroll
        for (int nt = 0; nt < 3; ++nt) {
          f4 a = {0.f,0.f,0.f,0.f};
#pragma unroll
          for (int kt = 0; kt < 2; ++kt) a = mm(Af[kt], Bf[nt][kt], a);
          int col = (wn*3+nt)*16 + lr;
#pragma unroll
          for (int r = 0; r < 4; ++r) {
            int row = mt*16 + lg*4 + r;
            if (row < NTOK) {
              float v = a[r] + pos_emb[row*DIMM + col] + (row==0 ? g_feat[col] : 0.f);
              sm[XS0 + row*XS_S + col] = f2b(v);
            }
          }
        }
      }
    }
  }
  __syncthreads();

  const f4 zero4 = {0.f,0.f,0.f,0.f};

  for (int L = 0; L < DEPTH; ++L) {
    const u16* wq = wqkv + (size_t)L*36*6*512;
    // ================= attention =================
    f4 oacc[4][3];
#pragma unroll
    for (int mi = 0; mi < 4; ++mi)
#pragma unroll
      for (int nt = 0; nt < 3; ++nt) oacc[mi][nt] = zero4;

    for (int h = 0; h < NHEAD; ++h) {
      // (A) qkv GEMM in 3 low-pressure passes (B[6]=24 VGPR live, not 72)
      // ---- pass Q ----
      {
        const int nt = h*4 + wn;
        bf8 B[6];
#pragma unroll
        for (int kt = 0; kt < 6; ++kt)
          B[kt] = *(const bf8*)&wq[((nt*6 + kt)*64 + lane)*8];
#pragma unroll
        for (int mi = 0; mi < 4; ++mi) {
          int mt = wm*4 + mi;
          if (mt < MT) {
            bf8 Af[6];
#pragma unroll
            for (int kt = 0; kt < 6; ++kt)
              Af[kt] = *(const bf8*)&sm[XS0 + (mt*16+lr)*XS_S + kt*32 + lg*8];
            f4 a = zero4;
#pragma unroll
            for (int kt = 0; kt < 6; ++kt) a = mm(Af[kt], B[kt], a);
            const int colq = wn*16 + lr;
#pragma unroll
            for (int r = 0; r < 4; ++r)
              sm[QH0 + (mt*16 + lg*4 + r)*QH_S + colq] = f2b(a[r]*0.125f); // pre-scaled
          }
        }
      }
      // ---- pass K ----
      {
        const int nt = 12 + h*4 + wn;
        bf8 B[6];
#pragma unroll
        for (int kt = 0; kt < 6; ++kt)
          B[kt] = *(const bf8*)&wq[((nt*6 + kt)*64 + lane)*8];
#pragma unroll
        for (int mi = 0; mi < 4; ++mi) {
          int mt = wm*4 + mi;
          if (mt < MT) {
            bf8 Af[6];
#pragma unroll
            for (int kt = 0; kt < 6; ++kt)
              Af[kt] = *(const bf8*)&sm[XS0 + (mt*16+lr)*XS_S + kt*32 + lg*8];
            f4 a = zero4;
#pragma unroll
            for (int kt = 0; kt < 6; ++kt) a = mm(Af[kt], B[kt], a);
            const int colq = wn*16 + lr;
#pragma unroll
            for (int r = 0; r < 4; ++r)
              sm[KH0 + (mt*16 + lg*4 + r)*QH_S + colq] = f2b(a[r]);
          }
        }
      }
      // ---- pass V (transposed store) ----
      {
        const int nt = 24 + h*4 + wn;
        bf8 B[6];
#pragma unroll
        for (int kt = 0; kt < 6; ++kt)
          B[kt] = *(const bf8*)&wq[((nt*6 + kt)*64 + lane)*8];
#pragma unroll
        for (int mi = 0; mi < 4; ++mi) {
          int mt = wm*4 + mi;
          if (mt < MT) {
            bf8 Af[6];
#pragma unroll
            for (int kt = 0; kt < 6; ++kt)
              Af[kt] = *(const bf8*)&sm[XS0 + (mt*16+lr)*XS_S + kt*32 + lg*8];
            f4 a = zero4;
#pragma unroll
            for (int kt = 0; kt < 6; ++kt) a = mm(Af[kt], B[kt], a);
            const int colq = wn*16 + lr;
#pragma unroll
            for (int r = 0; r < 4; ++r)
              sm[VT0 + colq*VT_S + (mt*16 + lg*4 + r)] = f2b(a[r]);
          }
        }
      }
      __syncthreads();

      // (B)+(C): per-wave M-tile: S = QK^T, softmax, P, O = P V (waves 0..6)
      {
        int mt = wv;
        if (mt < MT) {
          bf8 Aq[2];
#pragma unroll
          for (int ks = 0; ks < 2; ++ks)
            Aq[ks] = *(const bf8*)&sm[QH0 + (mt*16+lr)*QH_S + ks*32 + lg*8];
          f4 s[7];
#pragma unroll
          for (int kt = 0; kt < 7; ++kt) {
            f4 a = zero4;
#pragma unroll
            for (int ks = 0; ks < 2; ++ks) {
              bf8 Bk2 = *(const bf8*)&sm[KH0 + (kt*16+lr)*QH_S + ks*32 + lg*8];
              a = mm(Aq[ks], Bk2, a);
            }
            s[kt] = a;
          }
#pragma unroll
          for (int r = 0; r < 4; ++r) {
            const int row = mt*16 + lg*4 + r;
            float m = -1e30f;
#pragma unroll
            for (int kt = 0; kt < 7; ++kt) {
              float v = ((kt*16 + lr) < NTOK) ? s[kt][r] : -1e30f;
              m = fmaxf(m, v);
            }
            m = fmaxf(m, __shfl_xor(m, 1));
            m = fmaxf(m, __shfl_xor(m, 2));
            m = fmaxf(m, __shfl_xor(m, 4));
            m = fmaxf(m, __shfl_xor(m, 8));
            float p[7]; float sum = 0.f;
#pragma unroll
            for (int kt = 0; kt < 7; ++kt) {
              p[kt] = ((kt*16 + lr) < NTOK) ? __expf(s[kt][r] - m) : 0.f;
              sum += p[kt];
            }
            sum += __shfl_xor(sum, 1);
            sum += __shfl_xor(sum, 2);
            sum += __shfl_xor(sum, 4);
            sum += __shfl_xor(sum, 8);
            float inv = 1.0f / sum;
#pragma unroll
            for (int kt = 0; kt < 7; ++kt)
              sm[P0 + row*P_S + kt*16 + lr] = f2b(p[kt]*inv);
          }
          asm volatile("" ::: "memory");  // keep P writes before A-frag reads
          bf8 Ap[4];
#pragma unroll
          for (int ks = 0; ks < 4; ++ks)
            Ap[ks] = *(const bf8*)&sm[P0 + (mt*16+lr)*P_S + ks*32 + lg*8];
#pragma unroll
          for (int nt = 0; nt < 4; ++nt) {
            f4 a = zero4;
#pragma unroll
            for (int ks = 0; ks < 4; ++ks) {
              bf8 Bv2 = *(const bf8*)&sm[VT0 + (nt*16+lr)*VT_S + ks*32 + lg*8];
              a = mm(Ap[ks], Bv2, a);
            }
            const int col = nt*16 + lr;
#pragma unroll
            for (int r = 0; r < 4; ++r) {
              int row = mt*16 + lg*4 + r;
              sm[QH0 + row*QH_S + col] = f2b(a[r]);  // o_h into QH (own rows)
            }
          }
        }
      }
      __syncthreads();

      // (D) out-proj accumulate: oacc += o_h @ out_w[64h:64h+64, :]
      {
        bf8 Bo[3][2];
#pragma unroll
        for (int nt = 0; nt < 3; ++nt)
#pragma unroll
          for (int ks = 0; ks < 2; ++ks)
            Bo[nt][ks] = *(const bf8*)&wout[(size_t)(((L*12 + wn*3+nt)*6 + (h*2+ks))*64 + lane)*8];
#pragma unroll
        for (int mi = 0; mi < 4; ++mi) {
          int mt = wm*4 + mi;
          if (mt < MT) {
            bf8 Ao[2];
#pragma unroll
            for (int ks = 0; ks < 2; ++ks)
              Ao[ks] = *(const bf8*)&sm[QH0 + (mt*16+lr)*QH_S + ks*32 + lg*8];
#pragma unroll
            for (int nt = 0; nt < 3; ++nt)
#pragma unroll
              for (int ks = 0; ks < 2; ++ks)
                oacc[mi][nt] = mm(Ao[ks], Bo[nt][ks], oacc[mi][nt]);
          }
        }
      }
      __syncthreads();
    } // heads

    epilogue_ln(oacc, sm, rowred, ln1_g + L*DIMM, ln1_b + L*DIMM, out_b + L*DIMM, wm, wn, lg, lr);

    // ================= MLP =================
    f4 facc[4][3];
#pragma unroll
    for (int mi = 0; mi < 4; ++mi)
#pragma unroll
      for (int nt = 0; nt < 3; ++nt) facc[mi][nt] = zero4;

    for (int blk = 0; blk < 4; ++blk) {
      // GEMM1 + gelu -> h_lds (QH region, stride XS_S); nt-outer keeps B[6] only
#pragma unroll
      for (int nt = 0; nt < 3; ++nt) {
        bf8 B[6];
#pragma unroll
        for (int kt = 0; kt < 6; ++kt)
          B[kt] = *(const bf8*)&wff1[(size_t)(((L*48 + blk*12 + wn*3+nt)*6 + kt)*64 + lane)*8];
        float fb = ff1_b[L*MLPD + blk*192 + (wn*3+nt)*16 + lr];
#pragma unroll
        for (int mi = 0; mi < 4; ++mi) {
          int mt = wm*4 + mi;
          if (mt < MT) {
            bf8 Af[6];
#pragma unroll
            for (int kt = 0; kt < 6; ++kt)
              Af[kt] = *(const bf8*)&sm[XS0 + (mt*16+lr)*XS_S + kt*32 + lg*8];
            f4 a = zero4;
#pragma unroll
            for (int kt = 0; kt < 6; ++kt) a = mm(Af[kt], B[kt], a);
            int col = (wn*3+nt)*16 + lr;
#pragma unroll
            for (int r = 0; r < 4; ++r)
              sm[QH0 + (mt*16 + lg*4 + r)*XS_S + col] = f2b(gelu_f(a[r] + fb));
          }
        }
      }
      __syncthreads();
      // GEMM2 accumulate; nt-outer keeps B[6] only
#pragma unroll
      for (int nt = 0; nt < 3; ++nt) {
        bf8 B[6];
#pragma unroll
        for (int kt = 0; kt < 6; ++kt)
          B[kt] = *(const bf8*)&wff2[(size_t)(((L*12 + wn*3+nt)*24 + blk*6 + kt)*64 + lane)*8];
#pragma unroll
        for (int mi = 0; mi < 4; ++mi) {
          int mt = wm*4 + mi;
          if (mt < MT) {
            bf8 Ah[6];
#pragma unroll
            for (int kt = 0; kt < 6; ++kt)
              Ah[kt] = *(const bf8*)&sm[QH0 + (mt*16+lr)*XS_S + kt*32 + lg*8];
#pragma unroll
            for (int kt = 0; kt < 6; ++kt)
              facc[mi][nt] = mm(Ah[kt], B[kt], facc[mi][nt]);
          }
        }
      }
      __syncthreads();
    }

    epilogue_ln(facc, sm, rowred, ln2_g + L*DIMM, ln2_b + L*DIMM, ff2_b + L*DIMM, wm, wn, lg, lr);
  } // layers

  // ================= head =================
  float* yv = rowred;
  if (wv == 0) {
    float x0 = b2f(sm[XS0 + lane]);
    float x1 = b2f(sm[XS0 + 64 + lane]);
    float x2 = b2f(sm[XS0 + 128 + lane]);
    float s1 = x0+x1+x2;
    float s2 = x0*x0 + x1*x1 + x2*x2;
#pragma unroll
    for (int d = 1; d < 64; d <<= 1) { s1 += __shfl_xor(s1, d); s2 += __shfl_xor(s2, d); }
    float mean = s1*(1.0f/DIMM), var = s2*(1.0f/DIMM) - mean*mean;
    float rs = rsqrtf(var + 1e-5f);
    yv[lane]      = (x0-mean)*rs*hln_g[lane]      + hln_b[lane];
    yv[64+lane]   = (x1-mean)*rs*hln_g[64+lane]   + hln_b[64+lane];
    yv[128+lane]  = (x2-mean)*rs*hln_g[128+lane]  + hln_b[128+lane];
  }
  __syncthreads();
  if (tid < NCLS) {
    float acc = head_b[tid];
    for (int k = 0; k < DIMM; ++k) acc += yv[k] * head_w[k*NCLS + tid];
    out[(size_t)b*NCLS + tid] = acc;
  }
}

extern "C" void kernel_launch(void* const* d_in, const int* in_sizes, int n_in,
                              void* d_out, int out_size, void* d_ws, size_t ws_size,
                              hipStream_t stream) {
  const float* img    = (const float*)d_in[0];
  const float* lin_w  = (const float*)d_in[1];
  const float* g_feat = (const float*)d_in[2];
  const float* pos_emb= (const float*)d_in[3];
  const float* ln1_g  = (const float*)d_in[4];
  const float* ln1_b  = (const float*)d_in[5];
  const float* ln2_g  = (const float*)d_in[6];
  const float* ln2_b  = (const float*)d_in[7];
  const float* qkv_w  = (const float*)d_in[8];
  const float* out_w  = (const float*)d_in[9];
  const float* out_b  = (const float*)d_in[10];
  const float* ff1_w  = (const float*)d_in[11];
  const float* ff1_b  = (const float*)d_in[12];
  const float* ff2_w  = (const float*)d_in[13];
  const float* ff2_b  = (const float*)d_in[14];
  const float* hln_g  = (const float*)d_in[15];
  const float* hln_b  = (const float*)d_in[16];
  const float* head_w = (const float*)d_in[17];
  const float* head_b = (const float*)d_in[18];

  u16* ws   = (u16*)d_ws;
  u16* wlin = ws;                   // 1*12*2*512    = 12288
  u16* wqkv = wlin + 12288;         // 12*36*6*512   = 1327104
  u16* wout = wqkv + 1327104;       // 12*12*6*512   = 442368
  u16* wff1 = wout + 442368;        // 12*48*6*512   = 1769472
  u16* wff2 = wff1 + 1769472;       // 12*12*24*512  = 1769472

  struct PermArgs { const float* src; u16* dst; int layers, Kdim, Ndim, realK; };
  const PermArgs pa[5] = {
    { lin_w, wlin, 1, 64, 192, 40 },
    { qkv_w, wqkv, 12, 192, 576, 192 },
    { out_w, wout, 12, 192, 192, 192 },
    { ff1_w, wff1, 12, 192, 768, 192 },
    { ff2_w, wff2, 12, 768, 192, 768 },
  };
  for (int i = 0; i < 5; ++i) {
    int total = pa[i].layers * (pa[i].Ndim/16) * (pa[i].Kdim/32) * 512;
    hipLaunchKernelGGL(permw, dim3((total + 255)/256), dim3(256), 0, stream,
                       pa[i].src, pa[i].dst, total, pa[i].Kdim/32, pa[i].Ndim/16,
                       pa[i].realK, pa[i].Ndim);
  }

  hipFuncSetAttribute(reinterpret_cast<const void*>(vit_main),
                      hipFuncAttributeMaxDynamicSharedMemorySize, SMEM_BYTES);

  hipLaunchKernelGGL(vit_main, dim3(NBATCH), dim3(512), SMEM_BYTES, stream,
                     img, g_feat, pos_emb, ln1_g, ln1_b, ln2_g, ln2_b,
                     out_b, ff1_b, ff2_b, hln_g, hln_b, head_w, head_b,
                     wlin, wqkv, wout, wff1, wff2, (float*)d_out);
}

// Round 6
// 1573.166 us; speedup vs baseline: 1.3564x; 1.0294x over previous
//
#include <hip/hip_runtime.h>

typedef unsigned short u16;

#define DIMM   192
#define DEPTH  12
#define NHEAD  3
#define MLPD   768
#define NCLS   35
#define NTOK   99
#define TIMG   98
#define FIMG   40
#define NBATCH 512
#define MT     7

// LDS layout (u16 element offsets)
#define XS_S 200
#define QH_S 72
#define VT_S 136
#define P_S  136
#define XS0  0
#define QH0  22400
#define KH0  30464
#define VT0  38528
#define P0   47232
#define RR_BYTE 124928
#define SMEM_BYTES 128512

typedef __attribute__((ext_vector_type(8))) __bf16 bf8;
typedef __attribute__((ext_vector_type(4))) float  f4;

__device__ __forceinline__ float b2f(u16 u){
  union { float f; unsigned u; } v; v.u = ((unsigned)u) << 16; return v.f;
}
__device__ __forceinline__ u16 f2b(float f){
  __bf16 h = (__bf16)f;
  union { __bf16 h; u16 u; } v; v.h = h;
  return v.u;
}
__device__ __forceinline__ f4 mm(bf8 a, bf8 b, f4 c){
  return __builtin_amdgcn_mfma_f32_16x16x32_bf16(a, b, c, 0, 0, 0);
}
__device__ __forceinline__ float gelu_f(float x){
  float z = x * 0.7071067811865476f;
  float az = fabsf(z);
  float t = 1.0f / (1.0f + 0.3275911f * az);
  float poly = ((((1.061405429f*t - 1.453152027f)*t + 1.421413741f)*t
                 - 0.284496736f)*t + 0.254829592f)*t;
  float erfv = 1.0f - poly * __expf(-az*az);
  erfv = (z < 0.0f) ? -erfv : erfv;
  return 0.5f * x * (1.0f + erfv);
}

// Pre-permute weights: f32 [layers][K][N] -> bf16 fragment order
extern "C" __global__ void permw(const float* __restrict__ src, u16* __restrict__ dst,
                                 int total, int KT, int NT, int realK, int Ndim){
  int i = blockIdx.x * 256 + threadIdx.x;
  if (i >= total) return;
  int j = i & 7, l = (i >> 3) & 63;
  int rest = i >> 9;
  int kt = rest % KT; rest /= KT;
  int nt = rest % NT; int layer = rest / NT;
  int k = kt*32 + (l>>4)*8 + j;
  int n = nt*16 + (l&15);
  float v = (k < realK) ? src[((size_t)layer*realK + k)*Ndim + n] : 0.0f;
  union { float f; unsigned u; } w; w.f = v;
  unsigned r = w.u + 0x7FFFu + ((w.u >> 16) & 1u);
  dst[i] = (u16)(r >> 16);
}

extern "C" __global__
__attribute__((amdgpu_flat_work_group_size(512,512), amdgpu_waves_per_eu(2,2)))
void vit_main(
    const float* __restrict__ img,   const float* __restrict__ g_feat,
    const float* __restrict__ pos_emb,
    const float* __restrict__ ln1_g, const float* __restrict__ ln1_b,
    const float* __restrict__ ln2_g, const float* __restrict__ ln2_b,
    const float* __restrict__ out_b, const float* __restrict__ ff1_b,
    const float* __restrict__ ff2_b,
    const float* __restrict__ hln_g, const float* __restrict__ hln_b,
    const float* __restrict__ head_w, const float* __restrict__ head_b,
    const u16* __restrict__ wlin, const u16* __restrict__ wqkv,
    const u16* __restrict__ wout, const u16* __restrict__ wff1,
    const u16* __restrict__ wff2,
    float* __restrict__ out)
{
  extern __shared__ __align__(16) u16 sm[];
  float* rowred = (float*)((char*)sm + RR_BYTE);
  const int tid  = threadIdx.x;
  const int lane = tid & 63;
  const int wv   = tid >> 6;     // 0..7
  const int wm   = wv >> 2;      // M-group
  const int wn   = wv & 3;       // N-group
  const int lg   = lane >> 4;
  const int lr   = lane & 15;
  const int b    = blockIdx.x;

  // ---- precomputed LDS base pointers (all inner accesses = base + const imm) ----
  u16* const pA  = sm + XS0 + (wm*64 + lr)*XS_S + lg*8;        // x A-frag: +mi*16*XS_S + kt*32
  u16* const pH  = sm + QH0 + (wm*64 + lr)*XS_S + lg*8;        // h A-frag: +mi*16*XS_S + kt*32
  u16* const pOA = sm + QH0 + (wm*64 + lr)*QH_S + lg*8;        // o/img A-frag: +mi*16*QH_S + ks*32
  u16* const pQS = sm + QH0 + (wm*64 + lg*4)*QH_S + wn*16 + lr;// Q store: +(mi*16+r)*QH_S ; K store: +8064
  u16* const pVS = sm + VT0 + (wn*16 + lr)*VT_S + wm*64 + lg*4;// V^T store: +mi*16 + r
  u16* const pQA = sm + QH0 + (wv*16 + lr)*QH_S + lg*8;        // Aq read (phase B): +ks*32
  u16* const pKB = sm + KH0 + lr*QH_S + lg*8;                  // K B-frag: +kt*16*QH_S + ks*32
  u16* const pPS = sm + P0  + (wv*16 + lg*4)*P_S + lr;         // P store: +r*P_S + kt*16
  u16* const pPA = sm + P0  + (wv*16 + lr)*P_S + lg*8;         // Ap read: +ks*32
  u16* const pVB = sm + VT0 + lr*VT_S + lg*8;                  // V B-frag: +nt*16*VT_S + ks*32
  u16* const pOS = sm + QH0 + (wv*16 + lg*4)*QH_S + lr;        // o store: +r*QH_S + nt*16
  u16* const pXE = sm + XS0 + (wm*64 + lg*4)*XS_S + wn*48 + lr;// x epi rw: +(mi*16+r)*XS_S + nt*16 ; h store: +22400
  float* const pRR = rowred + (wm*64 + lg*4)*8;                // rowred read: +(mi*16+r)*8, float4 x2
  float* const pRS = pRR + wn*2;                               // rowred store: +(mi*16+r)*8 (+1)

  // zero all LDS once (pad regions must stay 0 forever)
  for (int i = tid; i < SMEM_BYTES/4; i += 512) ((unsigned*)sm)[i] = 0u;
  __syncthreads();

  const f4 zero4 = {0.f,0.f,0.f,0.f};

  auto epilogue_ln = [&](f4 (&acc)[4][3],
                         const float* gptr, const float* bptr, const float* biasptr){
    float gg[3], bb[3], ob[3];
#pragma unroll
    for (int nt = 0; nt < 3; ++nt) {
      int c = wn*48 + nt*16 + lr;
      gg[nt] = gptr[c]; bb[nt] = bptr[c]; ob[nt] = biasptr[c];
    }
#pragma unroll
    for (int mi = 0; mi < 4; ++mi) {
      if (mi < 3 || wm == 0) {
#pragma unroll
        for (int r = 0; r < 4; ++r) {
          float s1 = 0.f, s2 = 0.f;
#pragma unroll
          for (int nt = 0; nt < 3; ++nt) {
            float v = acc[mi][nt][r] + ob[nt] + b2f(pXE[(mi*16+r)*XS_S + nt*16]);
            acc[mi][nt][r] = v;
            s1 += v; s2 += v*v;
          }
          s1 += __shfl_xor(s1,1); s2 += __shfl_xor(s2,1);
          s1 += __shfl_xor(s1,2); s2 += __shfl_xor(s2,2);
          s1 += __shfl_xor(s1,4); s2 += __shfl_xor(s2,4);
          s1 += __shfl_xor(s1,8); s2 += __shfl_xor(s2,8);
          if (lr == 0) {
            pRS[(mi*16+r)*8 + 0] = s1;
            pRS[(mi*16+r)*8 + 1] = s2;
          }
        }
      }
    }
    __syncthreads();
#pragma unroll
    for (int mi = 0; mi < 4; ++mi) {
      if (mi < 3 || wm == 0) {
#pragma unroll
        for (int r = 0; r < 4; ++r) {
          float4 q0 = *(const float4*)&pRR[(mi*16+r)*8];
          float4 q1 = *(const float4*)&pRR[(mi*16+r)*8 + 4];
          float S1 = q0.x + q0.z + q1.x + q1.z;
          float S2 = q0.y + q0.w + q1.y + q1.w;
          float mean = S1 * (1.0f/DIMM);
          float var  = S2 * (1.0f/DIMM) - mean*mean;
          float rs = rsqrtf(var + 1e-5f);
          int row = wm*64 + mi*16 + lg*4 + r;
          if (row < NTOK) {
#pragma unroll
            for (int nt = 0; nt < 3; ++nt) {
              float y = (acc[mi][nt][r] - mean)*rs*gg[nt] + bb[nt];
              pXE[(mi*16+r)*XS_S + nt*16] = f2b(y);
            }
          }
        }
      }
    }
    __syncthreads();
  };

  // ---- patch embed: stage img (shifted +1 row; row0 = cls slot) into QH region ----
  const float* imgb = img + (size_t)b * (TIMG*FIMG);
  for (int i = tid; i < TIMG*FIMG; i += 512) {
    int r = i / FIMG, c = i - r*FIMG;
    sm[QH0 + (r+1)*QH_S + c] = f2b(imgb[i]);
  }
  __syncthreads();
  {
    const u16* wl = wlin + (size_t)(wn*3)*2*512 + lane*8;
    bf8 Bf[3][2];
#pragma unroll
    for (int nt = 0; nt < 3; ++nt)
#pragma unroll
      for (int kt = 0; kt < 2; ++kt)
        Bf[nt][kt] = *(const bf8*)&wl[(nt*2+kt)*512];
#pragma unroll
    for (int mi = 0; mi < 4; ++mi) {
      if (mi < 3 || wm == 0) {
        bf8 Af[2];
#pragma unroll
        for (int kt = 0; kt < 2; ++kt)
          Af[kt] = *(const bf8*)&pOA[mi*16*QH_S + kt*32];
#pragma unroll
        for (int nt = 0; nt < 3; ++nt) {
          f4 a = zero4;
#pragma unroll
          for (int kt = 0; kt < 2; ++kt) a = mm(Af[kt], Bf[nt][kt], a);
          int col = wn*48 + nt*16 + lr;
#pragma unroll
          for (int r = 0; r < 4; ++r) {
            int row = wm*64 + mi*16 + lg*4 + r;
            if (row < NTOK) {
              float v = a[r] + pos_emb[row*DIMM + col] + (row==0 ? g_feat[col] : 0.f);
              pXE[(mi*16+r)*XS_S + nt*16] = f2b(v);
            }
          }
        }
      }
    }
  }
  __syncthreads();

  for (int L = 0; L < DEPTH; ++L) {
    const u16* wq = wqkv + (size_t)L*36*6*512;
    // ================= attention =================
    f4 oacc[4][3];
#pragma unroll
    for (int mi = 0; mi < 4; ++mi)
#pragma unroll
      for (int nt = 0; nt < 3; ++nt) oacc[mi][nt] = zero4;

    for (int h = 0; h < NHEAD; ++h) {
      // ---- pass Q ----
      {
        const u16* wp = wq + ((size_t)(h*4 + wn)*6)*512 + lane*8;
        bf8 B[6];
#pragma unroll
        for (int kt = 0; kt < 6; ++kt) B[kt] = *(const bf8*)&wp[kt*512];
#pragma unroll
        for (int mi = 0; mi < 4; ++mi) {
          if (mi < 3 || wm == 0) {
            bf8 Af[6];
#pragma unroll
            for (int kt = 0; kt < 6; ++kt)
              Af[kt] = *(const bf8*)&pA[mi*16*XS_S + kt*32];
            f4 a = zero4;
#pragma unroll
            for (int kt = 0; kt < 6; ++kt) a = mm(Af[kt], B[kt], a);
#pragma unroll
            for (int r = 0; r < 4; ++r)
              pQS[(mi*16+r)*QH_S] = f2b(a[r]*0.125f);   // Q pre-scaled
          }
        }
      }
      // ---- pass K (store at pQS + (KH0-QH0)) ----
      {
        const u16* wp = wq + ((size_t)(12 + h*4 + wn)*6)*512 + lane*8;
        bf8 B[6];
#pragma unroll
        for (int kt = 0; kt < 6; ++kt) B[kt] = *(const bf8*)&wp[kt*512];
#pragma unroll
        for (int mi = 0; mi < 4; ++mi) {
          if (mi < 3 || wm == 0) {
            bf8 Af[6];
#pragma unroll
            for (int kt = 0; kt < 6; ++kt)
              Af[kt] = *(const bf8*)&pA[mi*16*XS_S + kt*32];
            f4 a = zero4;
#pragma unroll
            for (int kt = 0; kt < 6; ++kt) a = mm(Af[kt], B[kt], a);
#pragma unroll
            for (int r = 0; r < 4; ++r)
              pQS[(KH0-QH0) + (mi*16+r)*QH_S] = f2b(a[r]);
          }
        }
      }
      // ---- pass V (transposed store) ----
      {
        const u16* wp = wq + ((size_t)(24 + h*4 + wn)*6)*512 + lane*8;
        bf8 B[6];
#pragma unroll
        for (int kt = 0; kt < 6; ++kt) B[kt] = *(const bf8*)&wp[kt*512];
#pragma unroll
        for (int mi = 0; mi < 4; ++mi) {
          if (mi < 3 || wm == 0) {
            bf8 Af[6];
#pragma unroll
            for (int kt = 0; kt < 6; ++kt)
              Af[kt] = *(const bf8*)&pA[mi*16*XS_S + kt*32];
            f4 a = zero4;
#pragma unroll
            for (int kt = 0; kt < 6; ++kt) a = mm(Af[kt], B[kt], a);
#pragma unroll
            for (int r = 0; r < 4; ++r)
              pVS[mi*16 + r] = f2b(a[r]);
          }
        }
      }
      __syncthreads();

      // (B): per-wave M-tile: S = QK^T, softmax, P, O = P V (waves 0..6)
      if (wv < MT) {
        bf8 Aq[2];
#pragma unroll
        for (int ks = 0; ks < 2; ++ks)
          Aq[ks] = *(const bf8*)&pQA[ks*32];
        f4 s[7];
#pragma unroll
        for (int kt = 0; kt < 7; ++kt) {
          f4 a = zero4;
#pragma unroll
          for (int ks = 0; ks < 2; ++ks) {
            bf8 Bk2 = *(const bf8*)&pKB[kt*16*QH_S + ks*32];
            a = mm(Aq[ks], Bk2, a);
          }
          s[kt] = a;
        }
#pragma unroll
        for (int r = 0; r < 4; ++r) {
          float m = s[0][r];
#pragma unroll
          for (int kt = 1; kt < 6; ++kt) m = fmaxf(m, s[kt][r]);
          m = fmaxf(m, (lr < 3) ? s[6][r] : -1e30f);   // only cols 96..98 valid at kt=6
          m = fmaxf(m, __shfl_xor(m, 1));
          m = fmaxf(m, __shfl_xor(m, 2));
          m = fmaxf(m, __shfl_xor(m, 4));
          m = fmaxf(m, __shfl_xor(m, 8));
          float p[7]; float sum = 0.f;
#pragma unroll
          for (int kt = 0; kt < 6; ++kt) { p[kt] = __expf(s[kt][r] - m); sum += p[kt]; }
          p[6] = (lr < 3) ? __expf(s[6][r] - m) : 0.f;
          sum += p[6];
          sum += __shfl_xor(sum, 1);
          sum += __shfl_xor(sum, 2);
          sum += __shfl_xor(sum, 4);
          sum += __shfl_xor(sum, 8);
          float inv = 1.0f / sum;
#pragma unroll
          for (int kt = 0; kt < 7; ++kt)
            pPS[r*P_S + kt*16] = f2b(p[kt]*inv);
        }
        asm volatile("" ::: "memory");  // keep P writes before A-frag reads
        bf8 Ap[4];
#pragma unroll
        for (int ks = 0; ks < 4; ++ks)
          Ap[ks] = *(const bf8*)&pPA[ks*32];
#pragma unroll
        for (int nt = 0; nt < 4; ++nt) {
          f4 a = zero4;
#pragma unroll
          for (int ks = 0; ks < 4; ++ks) {
            bf8 Bv2 = *(const bf8*)&pVB[nt*16*VT_S + ks*32];
            a = mm(Ap[ks], Bv2, a);
          }
#pragma unroll
          for (int r = 0; r < 4; ++r)
            pOS[r*QH_S + nt*16] = f2b(a[r]);   // o_h into QH (own rows)
        }
      }
      __syncthreads();

      // (D) out-proj accumulate: oacc += o_h @ out_w[64h:64h+64, :]
      {
        const u16* wp = wout + (((size_t)(L*12 + wn*3)*6) + h*2)*512 + lane*8;
        bf8 Bo[3][2];
#pragma unroll
        for (int nt = 0; nt < 3; ++nt)
#pragma unroll
          for (int ks = 0; ks < 2; ++ks)
            Bo[nt][ks] = *(const bf8*)&wp[(nt*6 + ks)*512];
#pragma unroll
        for (int mi = 0; mi < 4; ++mi) {
          if (mi < 3 || wm == 0) {
            bf8 Ao[2];
#pragma unroll
            for (int ks = 0; ks < 2; ++ks)
              Ao[ks] = *(const bf8*)&pOA[mi*16*QH_S + ks*32];
#pragma unroll
            for (int nt = 0; nt < 3; ++nt)
#pragma unroll
              for (int ks = 0; ks < 2; ++ks)
                oacc[mi][nt] = mm(Ao[ks], Bo[nt][ks], oacc[mi][nt]);
          }
        }
      }
      __syncthreads();
    } // heads

    epilogue_ln(oacc, ln1_g + L*DIMM, ln1_b + L*DIMM, out_b + L*DIMM);

    // ================= MLP =================
    f4 facc[4][3];
#pragma unroll
    for (int mi = 0; mi < 4; ++mi)
#pragma unroll
      for (int nt = 0; nt < 3; ++nt) facc[mi][nt] = zero4;

    for (int blk = 0; blk < 4; ++blk) {
      { // GEMM1 + gelu -> h (QH region, stride XS_S); nt-outer keeps B[6] only
        const u16* wp = wff1 + ((size_t)(L*48 + blk*12 + wn*3)*6)*512 + lane*8;
        const float* fbp = ff1_b + L*MLPD + blk*192 + wn*48 + lr;
#pragma unroll
        for (int nt = 0; nt < 3; ++nt) {
          bf8 B[6];
#pragma unroll
          for (int kt = 0; kt < 6; ++kt) B[kt] = *(const bf8*)&wp[(nt*6+kt)*512];
          float fb = fbp[nt*16];
#pragma unroll
          for (int mi = 0; mi < 4; ++mi) {
            if (mi < 3 || wm == 0) {
              bf8 Af[6];
#pragma unroll
              for (int kt = 0; kt < 6; ++kt)
                Af[kt] = *(const bf8*)&pA[mi*16*XS_S + kt*32];
              f4 a = zero4;
#pragma unroll
              for (int kt = 0; kt < 6; ++kt) a = mm(Af[kt], B[kt], a);
#pragma unroll
              for (int r = 0; r < 4; ++r)
                pXE[(QH0-XS0) + (mi*16+r)*XS_S + nt*16] = f2b(gelu_f(a[r] + fb));
            }
          }
        }
      }
      __syncthreads();
      { // GEMM2 accumulate; nt-outer keeps B[6] only
        const u16* wp = wff2 + ((size_t)(L*12 + wn*3)*24 + blk*6)*512 + lane*8;
#pragma unroll
        for (int nt = 0; nt < 3; ++nt) {
          bf8 B[6];
#pragma unroll
          for (int kt = 0; kt < 6; ++kt) B[kt] = *(const bf8*)&wp[(nt*24+kt)*512];
#pragma unroll
          for (int mi = 0; mi < 4; ++mi) {
            if (mi < 3 || wm == 0) {
              bf8 Ah[6];
#pragma unroll
              for (int kt = 0; kt < 6; ++kt)
                Ah[kt] = *(const bf8*)&pH[mi*16*XS_S + kt*32];
#pragma unroll
              for (int kt = 0; kt < 6; ++kt)
                facc[mi][nt] = mm(Ah[kt], B[kt], facc[mi][nt]);
            }
          }
        }
      }
      __syncthreads();
    }

    epilogue_ln(facc, ln2_g + L*DIMM, ln2_b + L*DIMM, ff2_b + L*DIMM);
  } // layers

  // ================= head =================
  float* yv = rowred;
  if (wv == 0) {
    float x0 = b2f(sm[XS0 + lane]);
    float x1 = b2f(sm[XS0 + 64 + lane]);
    float x2 = b2f(sm[XS0 + 128 + lane]);
    float s1 = x0+x1+x2;
    float s2 = x0*x0 + x1*x1 + x2*x2;
#pragma unroll
    for (int d = 1; d < 64; d <<= 1) { s1 += __shfl_xor(s1, d); s2 += __shfl_xor(s2, d); }
    float mean = s1*(1.0f/DIMM), var = s2*(1.0f/DIMM) - mean*mean;
    float rs = rsqrtf(var + 1e-5f);
    yv[lane]      = (x0-mean)*rs*hln_g[lane]      + hln_b[lane];
    yv[64+lane]   = (x1-mean)*rs*hln_g[64+lane]   + hln_b[64+lane];
    yv[128+lane]  = (x2-mean)*rs*hln_g[128+lane]  + hln_b[128+lane];
  }
  __syncthreads();
  if (tid < NCLS) {
    float acc = head_b[tid];
    for (int k = 0; k < DIMM; ++k) acc += yv[k] * head_w[k*NCLS + tid];
    out[(size_t)b*NCLS + tid] = acc;
  }
}

extern "C" void kernel_launch(void* const* d_in, const int* in_sizes, int n_in,
                              void* d_out, int out_size, void* d_ws, size_t ws_size,
                              hipStream_t stream) {
  const float* img    = (const float*)d_in[0];
  const float* lin_w  = (const float*)d_in[1];
  const float* g_feat = (const float*)d_in[2];
  const float* pos_emb= (const float*)d_in[3];
  const float* ln1_g  = (const float*)d_in[4];
  const float* ln1_b  = (const float*)d_in[5];
  const float* ln2_g  = (const float*)d_in[6];
  const float* ln2_b  = (const float*)d_in[7];
  const float* qkv_w  = (const float*)d_in[8];
  const float* out_w  = (const float*)d_in[9];
  const float* out_b  = (const float*)d_in[10];
  const float* ff1_w  = (const float*)d_in[11];
  const float* ff1_b  = (const float*)d_in[12];
  const float* ff2_w  = (const float*)d_in[13];
  const float* ff2_b  = (const float*)d_in[14];
  const float* hln_g  = (const float*)d_in[15];
  const float* hln_b  = (const float*)d_in[16];
  const float* head_w = (const float*)d_in[17];
  const float* head_b = (const float*)d_in[18];

  u16* ws   = (u16*)d_ws;
  u16* wlin = ws;                   // 1*12*2*512    = 12288
  u16* wqkv = wlin + 12288;         // 12*36*6*512   = 1327104
  u16* wout = wqkv + 1327104;       // 12*12*6*512   = 442368
  u16* wff1 = wout + 442368;        // 12*48*6*512   = 1769472
  u16* wff2 = wff1 + 1769472;       // 12*12*24*512  = 1769472

  struct PermArgs { const float* src; u16* dst; int layers, Kdim, Ndim, realK; };
  const PermArgs pa[5] = {
    { lin_w, wlin, 1, 64, 192, 40 },
    { qkv_w, wqkv, 12, 192, 576, 192 },
    { out_w, wout, 12, 192, 192, 192 },
    { ff1_w, wff1, 12, 192, 768, 192 },
    { ff2_w, wff2, 12, 768, 192, 768 },
  };
  for (int i = 0; i < 5; ++i) {
    int total = pa[i].layers * (pa[i].Ndim/16) * (pa[i].Kdim/32) * 512;
    hipLaunchKernelGGL(permw, dim3((total + 255)/256), dim3(256), 0, stream,
                       pa[i].src, pa[i].dst, total, pa[i].Kdim/32, pa[i].Ndim/16,
                       pa[i].realK, pa[i].Ndim);
  }

  hipFuncSetAttribute(reinterpret_cast<const void*>(vit_main),
                      hipFuncAttributeMaxDynamicSharedMemorySize, SMEM_BYTES);

  hipLaunchKernelGGL(vit_main, dim3(NBATCH), dim3(512), SMEM_BYTES, stream,
                     img, g_feat, pos_emb, ln1_g, ln1_b, ln2_g, ln2_b,
                     out_b, ff1_b, ff2_b, hln_g, hln_b, head_w, head_b,
                     wlin, wqkv, wout, wff1, wff2, (float*)d_out);
}